// Round 1
// baseline (489.442 us; speedup 1.0000x reference)
//
#include <hip/hip_runtime.h>
#include <cstdint>
#include <cstddef>

#define NN 20000
#define NE 320000

typedef short short8 __attribute__((ext_vector_type(8)));
typedef float f32x4 __attribute__((ext_vector_type(4)));
typedef unsigned short u16;

__device__ __forceinline__ float b2f(u16 u) {
  union { unsigned int i; float f; } z; z.i = ((unsigned int)u) << 16; return z.f;
}
__device__ __forceinline__ u16 f2b(float f) {
  union { float f; unsigned int i; } z; z.f = f;
  unsigned int r = z.i + 0x7fffu + ((z.i >> 16) & 1u);
  return (u16)(r >> 16);
}
__device__ __forceinline__ float eluf(float v) {
  return v > 0.0f ? v : expm1f(v);
}

// ---------------- fp32 -> bf16 convert (features) ----------------
__global__ __launch_bounds__(256) void k_f2b(const float* __restrict__ in,
                                             u16* __restrict__ out, int n) {
  int i = (blockIdx.x * 256 + threadIdx.x) * 4;
  if (i >= n) return;
  float4 v = *reinterpret_cast<const float4*>(in + i);
  ushort4 o;
  o.x = f2b(v.x); o.y = f2b(v.y); o.z = f2b(v.z); o.w = f2b(v.w);
  *reinterpret_cast<ushort4*>(out + i) = o;
}

// ---------------- weight transpose + convert: W[K][N] -> Wt[N][K] bf16 ------
__global__ __launch_bounds__(256) void k_wt(const float* __restrict__ W,
                                            u16* __restrict__ Wt, int Kd, int Nd) {
  int idx = blockIdx.x * 256 + threadIdx.x;
  if (idx >= Kd * Nd) return;
  int n = idx / Kd, k = idx - n * Kd;
  Wt[idx] = f2b(W[(size_t)k * Nd + n]);
}

// ---------------- CSR build ----------------
__global__ __launch_bounds__(256) void k_hist(const int* __restrict__ dst,
                                              int* __restrict__ counts, int ne) {
  int i = blockIdx.x * 256 + threadIdx.x;
  if (i < ne) atomicAdd(&counts[dst[i]], 1);
}

__global__ __launch_bounds__(1024) void k_scan(const int* __restrict__ counts,
                                               int* __restrict__ rs, int n) {
  __shared__ int wsum[16];
  __shared__ int carry_s;
  int t = threadIdx.x;
  int l = t & 63, w = t >> 6;
  if (t == 0) carry_s = 0;
  __syncthreads();
  for (int base = 0; base < n; base += 1024) {
    int i = base + t;
    int v = (i < n) ? counts[i] : 0;
    int incl = v;
#pragma unroll
    for (int off = 1; off < 64; off <<= 1) {
      int u = __shfl_up(incl, off, 64);
      if (l >= off) incl += u;
    }
    if (l == 63) wsum[w] = incl;
    __syncthreads();
    int carry = carry_s;
    int wpre = 0;
    for (int k2 = 0; k2 < w; ++k2) wpre += wsum[k2];
    if (i < n) rs[i] = carry + wpre + incl - v;
    int tot = 0;
    if (t == 0) {
      for (int k2 = 0; k2 < 16; ++k2) tot += wsum[k2];
    }
    __syncthreads();
    if (t == 0) carry_s = carry + tot;
    __syncthreads();
  }
  if (threadIdx.x == 0) rs[n] = carry_s;
}

__global__ __launch_bounds__(256) void k_scatter(const int* __restrict__ src,
                                                 const int* __restrict__ dst,
                                                 int* __restrict__ cursor,
                                                 int* __restrict__ csr_src, int ne) {
  int i = blockIdx.x * 256 + threadIdx.x;
  if (i >= ne) return;
  int d = dst[i];
  int p = atomicAdd(&cursor[d], 1);
  csr_src[p] = src[i];
}

// ---------------- aggregation: h[n] = x[n] + sum_{s in in(n)} x[s] ----------
template <int D>
__global__ __launch_bounds__(64) void k_agg(const u16* __restrict__ x,
                                            const int* __restrict__ rs,
                                            const int* __restrict__ cs,
                                            u16* __restrict__ h) {
  constexpr int NC = D / 8;               // 16B chunks per row
  constexpr int RP = (NC + 63) / 64;      // chunks per lane
  int node = blockIdx.x;
  int l = threadIdx.x;
  float acc[RP][8];
#pragma unroll
  for (int r = 0; r < RP; ++r) {
    int c = r * 64 + l;
    if (c < NC) {
      short8 v = *reinterpret_cast<const short8*>(x + (size_t)node * D + c * 8);
#pragma unroll
      for (int q = 0; q < 8; ++q) acc[r][q] = b2f((u16)v[q]);
    } else {
#pragma unroll
      for (int q = 0; q < 8; ++q) acc[r][q] = 0.0f;
    }
  }
  int e0 = rs[node], e1 = rs[node + 1];
  for (int e = e0; e < e1; ++e) {
    int s = cs[e];
#pragma unroll
    for (int r = 0; r < RP; ++r) {
      int c = r * 64 + l;
      if (c < NC) {
        short8 v = *reinterpret_cast<const short8*>(x + (size_t)s * D + c * 8);
#pragma unroll
        for (int q = 0; q < 8; ++q) acc[r][q] += b2f((u16)v[q]);
      }
    }
  }
#pragma unroll
  for (int r = 0; r < RP; ++r) {
    int c = r * 64 + l;
    if (c < NC) {
      short8 o;
#pragma unroll
      for (int q = 0; q < 8; ++q) o[q] = (short)f2b(acc[r][q]);
      *reinterpret_cast<short8*>(h + (size_t)node * D + c * 8) = o;
    }
  }
}

// ---------------- GEMM: C = act(A[M][K] @ B[K][N] + bias), A bf16, Bt=[N][K] bf16
// 128x128 tile, BK=32, 4 waves (2x2 quadrants of 64x64), 16x16x32 bf16 MFMA.
template <int K, int N, int ACT, bool OUTF32>
__global__ __launch_bounds__(256) void k_gemm(const u16* __restrict__ A,
                                              const u16* __restrict__ Bt,
                                              const float* __restrict__ bias,
                                              void* __restrict__ outp, int M) {
  __shared__ __align__(16) u16 As[128 * 32];
  __shared__ __align__(16) u16 Bs[128 * 32];
  int t = threadIdx.x;
  int l = t & 63, w = t >> 6;
  int lm = l & 15, lk = l >> 4;
  int m0 = blockIdx.x * 128;
  int n0 = blockIdx.y * 128;
  int wm = (w >> 1) * 64, wn = (w & 1) * 64;
  f32x4 acc[4][4];
#pragma unroll
  for (int i = 0; i < 4; ++i)
#pragma unroll
    for (int j = 0; j < 4; ++j)
#pragma unroll
      for (int q = 0; q < 4; ++q) acc[i][j][q] = 0.0f;

  int wave_cbase = (t & ~63);
  for (int k0 = 0; k0 < K; k0 += 32) {
#pragma unroll
    for (int it = 0; it < 2; ++it) {
      int c = it * 256 + t;
      int row = c >> 2, ko = (c & 3) * 8;
      int ra = m0 + row; ra = ra < M ? ra : M - 1;
      int rb = n0 + row; rb = rb < N ? rb : N - 1;
      const u16* ga = A + (size_t)ra * K + k0 + ko;
      const u16* gb = Bt + (size_t)rb * K + k0 + ko;
      int wb = it * 256 + wave_cbase;
      __builtin_amdgcn_global_load_lds(
          (const __attribute__((address_space(1))) void*)ga,
          (__attribute__((address_space(3))) void*)(As + wb * 8), 16, 0, 0);
      __builtin_amdgcn_global_load_lds(
          (const __attribute__((address_space(1))) void*)gb,
          (__attribute__((address_space(3))) void*)(Bs + wb * 8), 16, 0, 0);
    }
    __syncthreads();
    short8 af[4], bf[4];
#pragma unroll
    for (int i = 0; i < 4; ++i) {
      af[i] = *reinterpret_cast<const short8*>(&As[(wm + i * 16 + lm) * 32 + lk * 8]);
      bf[i] = *reinterpret_cast<const short8*>(&Bs[(wn + i * 16 + lm) * 32 + lk * 8]);
    }
#pragma unroll
    for (int i = 0; i < 4; ++i)
#pragma unroll
      for (int j = 0; j < 4; ++j)
        acc[i][j] = __builtin_amdgcn_mfma_f32_16x16x32_bf16(af[i], bf[j], acc[i][j], 0, 0, 0);
    __syncthreads();
  }
  // epilogue: D row=(lk*4+q) within frag, col=lm (HW-verified C/D layout)
#pragma unroll
  for (int j = 0; j < 4; ++j) {
    int col = n0 + wn + j * 16 + lm;
    if (col >= N) continue;
    float bv = bias[col];
#pragma unroll
    for (int i = 0; i < 4; ++i) {
      int rb = m0 + wm + i * 16 + lk * 4;
#pragma unroll
      for (int q = 0; q < 4; ++q) {
        int r = rb + q;
        if (r >= M) continue;
        float v = acc[i][j][q] + bv;
        v = eluf(v);
        if (ACT == 2) v = eluf(v);
        if (OUTF32)
          ((float*)outp)[(size_t)r * N + col] = v;
        else
          ((u16*)outp)[(size_t)r * N + col] = f2b(v);
      }
    }
  }
}

extern "C" void kernel_launch(void* const* d_in, const int* in_sizes, int n_in,
                              void* d_out, int out_size, void* d_ws, size_t ws_size,
                              hipStream_t stream) {
  const float* features = (const float*)d_in[0];
  const int* eidx = (const int*)d_in[1];
  const float* w1a = (const float*)d_in[2];
  const float* b1a = (const float*)d_in[3];
  const float* w1b = (const float*)d_in[4];
  const float* b1b = (const float*)d_in[5];
  const float* w2a = (const float*)d_in[6];
  const float* b2a = (const float*)d_in[7];
  const float* w2b = (const float*)d_in[8];
  const float* b2b = (const float*)d_in[9];
  const float* w3a = (const float*)d_in[10];
  const float* b3a = (const float*)d_in[11];
  const float* w3b = (const float*)d_in[12];
  const float* b3b = (const float*)d_in[13];
  const float* wr = (const float*)d_in[14];
  const float* br = (const float*)d_in[15];

  char* ws = (char*)d_ws;
  u16* bufA = (u16*)(ws);                  // 20000*640 bf16 = 25.6e6 B
  u16* bufB = (u16*)(ws + 25600000);       // same
  u16* wrt = (u16*)(ws + 51200000);        // transposed bf16 weights
  u16* w1at = wrt + 256 * 256;
  u16* w1bt = w1at + 640 * 256;
  u16* w2at = w1bt + 640 * 640;
  u16* w2bt = w2at + 320 * 640;
  u16* w3at = w2bt + 320 * 320;
  u16* w3bt = w3at + 256 * 320;
  int* row_start = (int*)(ws + 53387264);  // NN+1 ints
  int* cursor = row_start + 20004;
  int* csr_src = cursor + NN;

  const int* esrc = eidx;
  const int* edst = eidx + NE;

  // CSR build (reused by all 3 layers)
  hipMemsetAsync(cursor, 0, NN * sizeof(int), stream);
  k_hist<<<(NE + 255) / 256, 256, 0, stream>>>(edst, cursor, NE);
  k_scan<<<1, 1024, 0, stream>>>(cursor, row_start, NN);
  hipMemcpyAsync(cursor, row_start, NN * sizeof(int), hipMemcpyDeviceToDevice, stream);
  k_scatter<<<(NE + 255) / 256, 256, 0, stream>>>(esrc, edst, cursor, csr_src, NE);

  // features -> bf16 (bufA), weights -> bf16 transposed
  k_f2b<<<(NN * 256 / 4 + 255) / 256, 256, 0, stream>>>(features, bufA, NN * 256);
  k_wt<<<(256 * 256 + 255) / 256, 256, 0, stream>>>(wr, wrt, 256, 256);
  k_wt<<<(256 * 640 + 255) / 256, 256, 0, stream>>>(w1a, w1at, 256, 640);
  k_wt<<<(640 * 640 + 255) / 256, 256, 0, stream>>>(w1b, w1bt, 640, 640);
  k_wt<<<(640 * 320 + 255) / 256, 256, 0, stream>>>(w2a, w2at, 640, 320);
  k_wt<<<(320 * 320 + 255) / 256, 256, 0, stream>>>(w2b, w2bt, 320, 320);
  k_wt<<<(320 * 256 + 255) / 256, 256, 0, stream>>>(w3a, w3at, 320, 256);
  k_wt<<<(256 * 256 + 255) / 256, 256, 0, stream>>>(w3b, w3bt, 256, 256);

  float* out_x = (float*)d_out;
  float* out_res = (float*)d_out + (size_t)NN * 256;

  dim3 g2(157, 2), g3(157, 3), g5(157, 5);

  // res = elu(X @ Wr + br)  (fp32 out, second half of d_out)
  k_gemm<256, 256, 1, true><<<g2, 256, 0, stream>>>(bufA, wrt, br, out_res, NN);
  // h0 = X + agg(X)
  k_agg<256><<<NN, 64, 0, stream>>>(bufA, row_start, csr_src, bufB);
  // t1 = elu(h0 @ w1a + b1a)
  k_gemm<256, 640, 1, false><<<g5, 256, 0, stream>>>(bufB, w1at, b1a, bufA, NN);
  // x1 = elu(elu(t1 @ w1b + b1b))   (layer output + outer elu)
  k_gemm<640, 640, 2, false><<<g5, 256, 0, stream>>>(bufA, w1bt, b1b, bufB, NN);
  // h1 = x1 + agg(x1)
  k_agg<640><<<NN, 64, 0, stream>>>(bufB, row_start, csr_src, bufA);
  // t2 = elu(h1 @ w2a + b2a)
  k_gemm<640, 320, 1, false><<<g3, 256, 0, stream>>>(bufA, w2at, b2a, bufB, NN);
  // x2 = elu(elu(t2 @ w2b + b2b))
  k_gemm<320, 320, 2, false><<<g3, 256, 0, stream>>>(bufB, w2bt, b2b, bufA, NN);
  // h2 = x2 + agg(x2)
  k_agg<320><<<NN, 64, 0, stream>>>(bufA, row_start, csr_src, bufB);
  // t3 = elu(h2 @ w3a + b3a)
  k_gemm<320, 256, 1, false><<<g2, 256, 0, stream>>>(bufB, w3at, b3a, bufA, NN);
  // x = elu(t3 @ w3b + b3b)  (fp32 out, first half of d_out)
  k_gemm<256, 256, 1, true><<<g2, 256, 0, stream>>>(bufA, w3bt, b3b, out_x, NN);
}

// Round 2
// 429.365 us; speedup vs baseline: 1.1399x; 1.1399x over previous
//
#include <hip/hip_runtime.h>
#include <cstdint>
#include <cstddef>

#define NN 20000
#define NE 320000

typedef short short8 __attribute__((ext_vector_type(8)));
typedef float f32x4 __attribute__((ext_vector_type(4)));
typedef unsigned short u16;

__device__ __forceinline__ float b2f(u16 u) {
  union { unsigned int i; float f; } z; z.i = ((unsigned int)u) << 16; return z.f;
}
__device__ __forceinline__ u16 f2b(float f) {
  union { float f; unsigned int i; } z; z.f = f;
  unsigned int r = z.i + 0x7fffu + ((z.i >> 16) & 1u);
  return (u16)(r >> 16);
}
__device__ __forceinline__ float eluf(float v) {
  return v > 0.0f ? v : expm1f(v);
}

// ---------------- fp32 -> bf16 convert (features) ----------------
__global__ __launch_bounds__(256) void k_f2b(const float* __restrict__ in,
                                             u16* __restrict__ out, int n) {
  int i = (blockIdx.x * 256 + threadIdx.x) * 4;
  if (i >= n) return;
  float4 v = *reinterpret_cast<const float4*>(in + i);
  ushort4 o;
  o.x = f2b(v.x); o.y = f2b(v.y); o.z = f2b(v.z); o.w = f2b(v.w);
  *reinterpret_cast<ushort4*>(out + i) = o;
}

// ---------------- weight transpose + convert: W[K][N] -> Wt[N][K] bf16 ------
__global__ __launch_bounds__(256) void k_wt(const float* __restrict__ W,
                                            u16* __restrict__ Wt, int Kd, int Nd) {
  int idx = blockIdx.x * 256 + threadIdx.x;
  if (idx >= Kd * Nd) return;
  int n = idx / Kd, k = idx - n * Kd;
  Wt[idx] = f2b(W[(size_t)k * Nd + n]);
}

// ---------------- CSR build ----------------
__global__ __launch_bounds__(256) void k_hist(const int* __restrict__ dst,
                                              int* __restrict__ counts, int ne) {
  int i = blockIdx.x * 256 + threadIdx.x;
  if (i < ne) atomicAdd(&counts[dst[i]], 1);
}

__global__ __launch_bounds__(1024) void k_scan(const int* __restrict__ counts,
                                               int* __restrict__ rs, int n) {
  __shared__ int wsum[16];
  __shared__ int carry_s;
  int t = threadIdx.x;
  int l = t & 63, w = t >> 6;
  if (t == 0) carry_s = 0;
  __syncthreads();
  for (int base = 0; base < n; base += 1024) {
    int i = base + t;
    int v = (i < n) ? counts[i] : 0;
    int incl = v;
#pragma unroll
    for (int off = 1; off < 64; off <<= 1) {
      int u = __shfl_up(incl, off, 64);
      if (l >= off) incl += u;
    }
    if (l == 63) wsum[w] = incl;
    __syncthreads();
    int carry = carry_s;
    int wpre = 0;
    for (int k2 = 0; k2 < w; ++k2) wpre += wsum[k2];
    if (i < n) rs[i] = carry + wpre + incl - v;
    int tot = 0;
    if (t == 0) {
      for (int k2 = 0; k2 < 16; ++k2) tot += wsum[k2];
    }
    __syncthreads();
    if (t == 0) carry_s = carry + tot;
    __syncthreads();
  }
  if (threadIdx.x == 0) rs[n] = carry_s;
}

__global__ __launch_bounds__(256) void k_scatter(const int* __restrict__ src,
                                                 const int* __restrict__ dst,
                                                 int* __restrict__ cursor,
                                                 int* __restrict__ csr_src, int ne) {
  int i = blockIdx.x * 256 + threadIdx.x;
  if (i >= ne) return;
  int d = dst[i];
  int p = atomicAdd(&cursor[d], 1);
  csr_src[p] = src[i];
}

// ------- aggregation: h[n] = x[n] + sum_{s in in(n)} x[s], flat (node,chunk) -
template <int D>
__global__ __launch_bounds__(256) void k_agg(const u16* __restrict__ x,
                                             const int* __restrict__ rs,
                                             const int* __restrict__ cs,
                                             u16* __restrict__ h) {
  constexpr int NC = D / 8;  // 16B chunks per row
  int tid = blockIdx.x * 256 + threadIdx.x;
  if (tid >= NN * NC) return;
  int node = tid / NC;
  int c = tid - node * NC;
  size_t co = (size_t)c * 8;
  float acc[8];
  {
    short8 v = *reinterpret_cast<const short8*>(x + (size_t)node * D + co);
#pragma unroll
    for (int q = 0; q < 8; ++q) acc[q] = b2f((u16)v[q]);
  }
  int e0 = rs[node], e1 = rs[node + 1];
  for (int e = e0; e < e1; ++e) {
    int s = cs[e];
    short8 v = *reinterpret_cast<const short8*>(x + (size_t)s * D + co);
#pragma unroll
    for (int q = 0; q < 8; ++q) acc[q] += b2f((u16)v[q]);
  }
  short8 o;
#pragma unroll
  for (int q = 0; q < 8; ++q) o[q] = (short)f2b(acc[q]);
  *reinterpret_cast<short8*>(h + (size_t)node * D + co) = o;
}

// ---------------- GEMM: C = act(A[M][K] @ B[K][N] + bias) ----------------
// A bf16 [M][K], Bt bf16 [N][K]. 128x128 tile, BK=32 double-buffered,
// 4 waves (2x2 of 64x64), 16x16x32 bf16 MFMA, swizzled LDS, XCD-chunked grid.
template <int K, int N, int ACT, bool OUTF32>
__global__ __launch_bounds__(256) void k_gemm(const u16* __restrict__ A,
                                              const u16* __restrict__ Bt,
                                              const float* __restrict__ bias,
                                              void* __restrict__ outp, int M) {
  constexpr int NBY = (N + 127) / 128;
  constexpr int NK = K / 32;
  __shared__ __align__(16) u16 smem[16384];  // As[2][4096] | Bs[2][4096] (32KB)
  u16* As = smem;
  u16* Bs = smem + 8192;
  int t = threadIdx.x;
  int l = t & 63, w = t >> 6;
  int lm = l & 15, lk = l >> 4;

  // bijective XCD-chunked swizzle (m204): contiguous wg range per XCD,
  // n0 varies fastest within an XCD -> A-panels stay L2-resident per XCD.
  int nb = gridDim.x;
  int q8 = nb >> 3, r8 = nb & 7;
  int orig = blockIdx.x;
  int xcd = orig & 7, idx = orig >> 3;
  int wg = (xcd < r8 ? xcd * (q8 + 1) : r8 * (q8 + 1) + (xcd - r8) * q8) + idx;
  int m0 = (wg / NBY) * 128;
  int n0 = (wg % NBY) * 128;
  int wm = (w >> 1) * 64, wn = (w & 1) * 64;

  f32x4 acc[4][4];
#pragma unroll
  for (int i = 0; i < 4; ++i)
#pragma unroll
    for (int j = 0; j < 4; ++j)
#pragma unroll
      for (int qq = 0; qq < 4; ++qq) acc[i][j][qq] = 0.0f;

  // stage one 128x32 K-slab of A and B into LDS buf, k-chunk pre-swizzled in
  // the GLOBAL source so the linear global_load_lds dest + swizzled ds_read
  // are consistent (rule #21).
  auto stage = [&](int buf, int kt) {
    int k0 = kt * 32;
#pragma unroll
    for (int it = 0; it < 2; ++it) {
      int c = it * 256 + t;
      int row = c >> 2;
      int kc = (c & 3) ^ ((c >> 3) & 3);  // slot p holds chunk p ^ ((row>>1)&3)
      int ra = m0 + row; ra = ra < M ? ra : M - 1;
      int rb = n0 + row; rb = rb < N ? rb : N - 1;
      const u16* ga = A + (size_t)ra * K + k0 + kc * 8;
      const u16* gb = Bt + (size_t)rb * K + k0 + kc * 8;
      __builtin_amdgcn_global_load_lds(
          (const __attribute__((address_space(1))) void*)ga,
          (__attribute__((address_space(3))) void*)(As + buf * 4096 + c * 8), 16, 0, 0);
      __builtin_amdgcn_global_load_lds(
          (const __attribute__((address_space(1))) void*)gb,
          (__attribute__((address_space(3))) void*)(Bs + buf * 4096 + c * 8), 16, 0, 0);
    }
  };

  // swizzled read slot: logical chunk lk lives at physical slot lk^((row>>1)&3);
  // row = (multiple of 16) + lm  =>  ((row>>1)&3) == ((lm>>1)&3), per-lane const.
  int kidx = (lk ^ ((lm >> 1) & 3)) * 8;

  stage(0, 0);
  __syncthreads();
  for (int kt = 0; kt < NK; ++kt) {
    int buf = kt & 1;
    if (kt + 1 < NK) stage(buf ^ 1, kt + 1);
    short8 af[4], bf[4];
#pragma unroll
    for (int i = 0; i < 4; ++i) {
      af[i] = *reinterpret_cast<const short8*>(As + buf * 4096 + (wm + i * 16 + lm) * 32 + kidx);
      bf[i] = *reinterpret_cast<const short8*>(Bs + buf * 4096 + (wn + i * 16 + lm) * 32 + kidx);
    }
#pragma unroll
    for (int i = 0; i < 4; ++i)
#pragma unroll
      for (int j = 0; j < 4; ++j)
        acc[i][j] = __builtin_amdgcn_mfma_f32_16x16x32_bf16(af[i], bf[j], acc[i][j], 0, 0, 0);
    __syncthreads();
  }

  // epilogue. C/D frag layout: row = i*16 + lk*4 + qq, col = j*16 + lm.
  if (!OUTF32) {
    // bf16 out: stage wave's 64x64 u16 tile in LDS (reuses staging smem; all
    // ds_reads drained by the final barrier), then store contiguous 16B chunks.
    u16* ep = smem + w * 4096;
#pragma unroll
    for (int j = 0; j < 4; ++j) {
      int col = n0 + wn + j * 16 + lm;
      float bv = bias[col < N ? col : N - 1];
#pragma unroll
      for (int i = 0; i < 4; ++i)
#pragma unroll
        for (int qq = 0; qq < 4; ++qq) {
          float v = acc[i][j][qq] + bv;
          v = eluf(v);
          if (ACT == 2) v = eluf(v);
          ep[(i * 16 + lk * 4 + qq) * 64 + j * 16 + lm] = f2b(v);
        }
    }
    __syncthreads();
    u16* op = (u16*)outp;
#pragma unroll
    for (int u = 0; u < 8; ++u) {
      int rrow = m0 + wm + u * 8 + (l >> 3);
      int col = n0 + wn + (l & 7) * 8;
      if (rrow < M && col < N)
        *reinterpret_cast<short8*>(op + (size_t)rrow * N + col) =
            *reinterpret_cast<const short8*>(ep + u * 512 + l * 8);
    }
  } else {
    // fp32 out: 16 lanes x 4B = full 64B line per store instruction.
    float* op = (float*)outp;
#pragma unroll
    for (int j = 0; j < 4; ++j) {
      int col = n0 + wn + j * 16 + lm;
      if (col >= N) continue;
      float bv = bias[col];
#pragma unroll
      for (int i = 0; i < 4; ++i) {
        int rb = m0 + wm + i * 16 + lk * 4;
#pragma unroll
        for (int qq = 0; qq < 4; ++qq) {
          int rr = rb + qq;
          if (rr >= M) continue;
          float v = acc[i][j][qq] + bv;
          v = eluf(v);
          if (ACT == 2) v = eluf(v);
          op[(size_t)rr * N + col] = v;
        }
      }
    }
  }
}

extern "C" void kernel_launch(void* const* d_in, const int* in_sizes, int n_in,
                              void* d_out, int out_size, void* d_ws, size_t ws_size,
                              hipStream_t stream) {
  const float* features = (const float*)d_in[0];
  const int* eidx = (const int*)d_in[1];
  const float* w1a = (const float*)d_in[2];
  const float* b1a = (const float*)d_in[3];
  const float* w1b = (const float*)d_in[4];
  const float* b1b = (const float*)d_in[5];
  const float* w2a = (const float*)d_in[6];
  const float* b2a = (const float*)d_in[7];
  const float* w2b = (const float*)d_in[8];
  const float* b2b = (const float*)d_in[9];
  const float* w3a = (const float*)d_in[10];
  const float* b3a = (const float*)d_in[11];
  const float* w3b = (const float*)d_in[12];
  const float* b3b = (const float*)d_in[13];
  const float* wr = (const float*)d_in[14];
  const float* br = (const float*)d_in[15];

  char* ws = (char*)d_ws;
  u16* bufA = (u16*)(ws);                  // 20000*640 bf16 = 25.6e6 B
  u16* bufB = (u16*)(ws + 25600000);       // same
  u16* wrt = (u16*)(ws + 51200000);        // transposed bf16 weights
  u16* w1at = wrt + 256 * 256;
  u16* w1bt = w1at + 640 * 256;
  u16* w2at = w1bt + 640 * 640;
  u16* w2bt = w2at + 320 * 640;
  u16* w3at = w2bt + 320 * 320;
  u16* w3bt = w3at + 256 * 320;
  int* row_start = (int*)(ws + 53387264);  // NN+1 ints
  int* cursor = row_start + 20004;
  int* csr_src = cursor + NN;

  const int* esrc = eidx;
  const int* edst = eidx + NE;

  // CSR build (reused by all 3 layers)
  hipMemsetAsync(cursor, 0, NN * sizeof(int), stream);
  k_hist<<<(NE + 255) / 256, 256, 0, stream>>>(edst, cursor, NE);
  k_scan<<<1, 1024, 0, stream>>>(cursor, row_start, NN);
  hipMemcpyAsync(cursor, row_start, NN * sizeof(int), hipMemcpyDeviceToDevice, stream);
  k_scatter<<<(NE + 255) / 256, 256, 0, stream>>>(esrc, edst, cursor, csr_src, NE);

  // features -> bf16 (bufA), weights -> bf16 transposed
  k_f2b<<<(NN * 256 / 4 + 255) / 256, 256, 0, stream>>>(features, bufA, NN * 256);
  k_wt<<<(256 * 256 + 255) / 256, 256, 0, stream>>>(wr, wrt, 256, 256);
  k_wt<<<(256 * 640 + 255) / 256, 256, 0, stream>>>(w1a, w1at, 256, 640);
  k_wt<<<(640 * 640 + 255) / 256, 256, 0, stream>>>(w1b, w1bt, 640, 640);
  k_wt<<<(640 * 320 + 255) / 256, 256, 0, stream>>>(w2a, w2at, 640, 320);
  k_wt<<<(320 * 320 + 255) / 256, 256, 0, stream>>>(w2b, w2bt, 320, 320);
  k_wt<<<(320 * 256 + 255) / 256, 256, 0, stream>>>(w3a, w3at, 320, 256);
  k_wt<<<(256 * 256 + 255) / 256, 256, 0, stream>>>(w3b, w3bt, 256, 256);

  float* out_x = (float*)d_out;
  float* out_res = (float*)d_out + (size_t)NN * 256;

  // res = elu(X @ Wr + br)  (fp32 out, second half of d_out)
  k_gemm<256, 256, 1, true><<<dim3(157 * 2), 256, 0, stream>>>(bufA, wrt, br, out_res, NN);
  // h0 = X + agg(X)
  k_agg<256><<<(NN * 32 + 255) / 256, 256, 0, stream>>>(bufA, row_start, csr_src, bufB);
  // t1 = elu(h0 @ w1a + b1a)
  k_gemm<256, 640, 1, false><<<dim3(157 * 5), 256, 0, stream>>>(bufB, w1at, b1a, bufA, NN);
  // x1 = elu(elu(t1 @ w1b + b1b))
  k_gemm<640, 640, 2, false><<<dim3(157 * 5), 256, 0, stream>>>(bufA, w1bt, b1b, bufB, NN);
  // h1 = x1 + agg(x1)
  k_agg<640><<<(NN * 80 + 255) / 256, 256, 0, stream>>>(bufB, row_start, csr_src, bufA);
  // t2 = elu(h1 @ w2a + b2a)
  k_gemm<640, 320, 1, false><<<dim3(157 * 3), 256, 0, stream>>>(bufA, w2at, b2a, bufB, NN);
  // x2 = elu(elu(t2 @ w2b + b2b))
  k_gemm<320, 320, 2, false><<<dim3(157 * 3), 256, 0, stream>>>(bufB, w2bt, b2b, bufA, NN);
  // h2 = x2 + agg(x2)
  k_agg<320><<<(NN * 40 + 255) / 256, 256, 0, stream>>>(bufA, row_start, csr_src, bufB);
  // t3 = elu(h2 @ w3a + b3a)
  k_gemm<320, 256, 1, false><<<dim3(157 * 2), 256, 0, stream>>>(bufB, w3at, b3a, bufA, NN);
  // x = elu(t3 @ w3b + b3b)  (fp32 out, first half of d_out)
  k_gemm<256, 256, 1, true><<<dim3(157 * 2), 256, 0, stream>>>(bufA, w3bt, b3b, out_x, NN);
}

// Round 3
// 351.054 us; speedup vs baseline: 1.3942x; 1.2231x over previous
//
#include <hip/hip_runtime.h>
#include <cstdint>
#include <cstddef>

#define NN 20000
#define NE 320000

typedef short short8 __attribute__((ext_vector_type(8)));
typedef float f32x4 __attribute__((ext_vector_type(4)));
typedef unsigned short u16;

__device__ __forceinline__ float b2f(u16 u) {
  union { unsigned int i; float f; } z; z.i = ((unsigned int)u) << 16; return z.f;
}
__device__ __forceinline__ u16 f2b(float f) {
  union { float f; unsigned int i; } z; z.f = f;
  unsigned int r = z.i + 0x7fffu + ((z.i >> 16) & 1u);
  return (u16)(r >> 16);
}
__device__ __forceinline__ float eluf(float v) {
  return v > 0.0f ? v : expm1f(v);
}

// ---------------- fp32 -> bf16 convert (features) ----------------
__global__ __launch_bounds__(256) void k_f2b(const float* __restrict__ in,
                                             u16* __restrict__ out, int n) {
  int i = (blockIdx.x * 256 + threadIdx.x) * 4;
  if (i >= n) return;
  float4 v = *reinterpret_cast<const float4*>(in + i);
  ushort4 o;
  o.x = f2b(v.x); o.y = f2b(v.y); o.z = f2b(v.z); o.w = f2b(v.w);
  *reinterpret_cast<ushort4*>(out + i) = o;
}

// ---------------- weight transpose + convert: W[K][N] -> Wt[N][K] bf16 ------
__global__ __launch_bounds__(256) void k_wt(const float* __restrict__ W,
                                            u16* __restrict__ Wt, int Kd, int Nd) {
  int idx = blockIdx.x * 256 + threadIdx.x;
  if (idx >= Kd * Nd) return;
  int n = idx / Kd, k = idx - n * Kd;
  Wt[idx] = f2b(W[(size_t)k * Nd + n]);
}

// ---------------- CSR build ----------------
__global__ __launch_bounds__(256) void k_hist(const int* __restrict__ dst,
                                              int* __restrict__ counts, int ne) {
  int i = blockIdx.x * 256 + threadIdx.x;
  if (i < ne) atomicAdd(&counts[dst[i]], 1);
}

__global__ __launch_bounds__(1024) void k_scan(const int* __restrict__ counts,
                                               int* __restrict__ rs, int n) {
  __shared__ int wsum[16];
  __shared__ int carry_s;
  int t = threadIdx.x;
  int l = t & 63, w = t >> 6;
  if (t == 0) carry_s = 0;
  __syncthreads();
  for (int base = 0; base < n; base += 1024) {
    int i = base + t;
    int v = (i < n) ? counts[i] : 0;
    int incl = v;
#pragma unroll
    for (int off = 1; off < 64; off <<= 1) {
      int u = __shfl_up(incl, off, 64);
      if (l >= off) incl += u;
    }
    if (l == 63) wsum[w] = incl;
    __syncthreads();
    int carry = carry_s;
    int wpre = 0;
    for (int k2 = 0; k2 < w; ++k2) wpre += wsum[k2];
    if (i < n) rs[i] = carry + wpre + incl - v;
    int tot = 0;
    if (t == 0) {
      for (int k2 = 0; k2 < 16; ++k2) tot += wsum[k2];
    }
    __syncthreads();
    if (t == 0) carry_s = carry + tot;
    __syncthreads();
  }
  if (threadIdx.x == 0) rs[n] = carry_s;
}

__global__ __launch_bounds__(256) void k_scatter(const int* __restrict__ src,
                                                 const int* __restrict__ dst,
                                                 int* __restrict__ cursor,
                                                 int* __restrict__ csr_src, int ne) {
  int i = blockIdx.x * 256 + threadIdx.x;
  if (i >= ne) return;
  int d = dst[i];
  int p = atomicAdd(&cursor[d], 1);
  csr_src[p] = src[i];
}

// ---- aggregation: h[n] = f(x[n] + sum_{s in in(n)} x[s]), flat (node,chunk) -
// ACT=0: f = identity (no bias).  ACT=1: f = elu(v + bias).
template <int D, int ACT>
__global__ __launch_bounds__(256) void k_agg(const u16* __restrict__ x,
                                             const int* __restrict__ rs,
                                             const int* __restrict__ cs,
                                             const float* __restrict__ bias,
                                             u16* __restrict__ h) {
  constexpr int NC = D / 8;  // 16B chunks per row
  int tid = blockIdx.x * 256 + threadIdx.x;
  if (tid >= NN * NC) return;
  int node = tid / NC;
  int c = tid - node * NC;
  const u16* xp = x + (size_t)c * 8;
  float acc[8];
  {
    short8 v = *reinterpret_cast<const short8*>(xp + (size_t)node * D);
#pragma unroll
    for (int q = 0; q < 8; ++q) acc[q] = b2f((u16)v[q]);
  }
  int e0 = rs[node], e1 = rs[node + 1];
  int e = e0;
  // 4-wide unroll: 4 independent index loads + 4 independent gathers in flight
  for (; e + 4 <= e1; e += 4) {
    int s0 = cs[e], s1 = cs[e + 1], s2 = cs[e + 2], s3 = cs[e + 3];
    short8 v0 = *reinterpret_cast<const short8*>(xp + (size_t)s0 * D);
    short8 v1 = *reinterpret_cast<const short8*>(xp + (size_t)s1 * D);
    short8 v2 = *reinterpret_cast<const short8*>(xp + (size_t)s2 * D);
    short8 v3 = *reinterpret_cast<const short8*>(xp + (size_t)s3 * D);
#pragma unroll
    for (int q = 0; q < 8; ++q)
      acc[q] += (b2f((u16)v0[q]) + b2f((u16)v1[q])) + (b2f((u16)v2[q]) + b2f((u16)v3[q]));
  }
  for (; e < e1; ++e) {
    int s = cs[e];
    short8 v = *reinterpret_cast<const short8*>(xp + (size_t)s * D);
#pragma unroll
    for (int q = 0; q < 8; ++q) acc[q] += b2f((u16)v[q]);
  }
  if (ACT == 1) {
    float4 b0 = *reinterpret_cast<const float4*>(bias + c * 8);
    float4 b1 = *reinterpret_cast<const float4*>(bias + c * 8 + 4);
    acc[0] = eluf(acc[0] + b0.x); acc[1] = eluf(acc[1] + b0.y);
    acc[2] = eluf(acc[2] + b0.z); acc[3] = eluf(acc[3] + b0.w);
    acc[4] = eluf(acc[4] + b1.x); acc[5] = eluf(acc[5] + b1.y);
    acc[6] = eluf(acc[6] + b1.z); acc[7] = eluf(acc[7] + b1.w);
  }
  short8 o;
#pragma unroll
  for (int q = 0; q < 8; ++q) o[q] = (short)f2b(acc[q]);
  *reinterpret_cast<short8*>(h + (size_t)node * D + (size_t)c * 8) = o;
}

// ---------------- GEMM: C = act(A[M][K] @ B[K][N] + bias) ----------------
// A bf16 [M][K], Bt bf16 [N][K]. BMx128 tile, BK=32 double-buffered,
// 4 waves (2x2), 16x16x32 bf16 MFMA, swizzled LDS, XCD-chunked grid.
// ACT: 0 = none (no bias), 1 = elu(v+bias), 2 = elu(elu(v+bias)).
template <int BM, int K, int N, int ACT, bool OUTF32>
__global__ __launch_bounds__(256) void k_gemm(const u16* __restrict__ A,
                                              const u16* __restrict__ Bt,
                                              const float* __restrict__ bias,
                                              void* __restrict__ outp, int M) {
  constexpr int NBY = (N + 127) / 128;
  constexpr int NK = K / 32;
  constexpr int ABUF = BM * 32;   // u16 per A LDS buffer
  constexpr int MI = BM / 32;     // acc i-extent per wave (2 or 4)
  __shared__ __align__(16) u16 smem[2 * ABUF + 8192];
  u16* As = smem;
  u16* Bs = smem + 2 * ABUF;
  int t = threadIdx.x;
  int l = t & 63, w = t >> 6;
  int lm = l & 15, lk = l >> 4;

  // bijective XCD-chunked swizzle (m204)
  int nb = gridDim.x;
  int q8 = nb >> 3, r8 = nb & 7;
  int orig = blockIdx.x;
  int xcd = orig & 7, idx = orig >> 3;
  int wg = (xcd < r8 ? xcd * (q8 + 1) : r8 * (q8 + 1) + (xcd - r8) * q8) + idx;
  int m0 = (wg / NBY) * BM;
  int n0 = (wg % NBY) * 128;
  int wm = (w >> 1) * (BM / 2), wn = (w & 1) * 64;

  f32x4 acc[MI][4];
#pragma unroll
  for (int i = 0; i < MI; ++i)
#pragma unroll
    for (int j = 0; j < 4; ++j)
#pragma unroll
      for (int qq = 0; qq < 4; ++qq) acc[i][j][qq] = 0.0f;

  // stage one K-slab; k-chunk pre-swizzled in the GLOBAL source (rule #21)
  auto stage = [&](int buf, int kt) {
    int k0 = kt * 32;
#pragma unroll
    for (int it = 0; it < BM / 64; ++it) {  // A: BM*32 u16 / (256 lanes * 8)
      int c = it * 256 + t;
      int row = c >> 2;
      int kc = (c & 3) ^ ((c >> 3) & 3);
      int ra = m0 + row; ra = ra < M ? ra : M - 1;
      const u16* ga = A + (size_t)ra * K + k0 + kc * 8;
      __builtin_amdgcn_global_load_lds(
          (const __attribute__((address_space(1))) void*)ga,
          (__attribute__((address_space(3))) void*)(As + buf * ABUF + c * 8), 16, 0, 0);
    }
#pragma unroll
    for (int it = 0; it < 2; ++it) {        // B: 128*32 u16
      int c = it * 256 + t;
      int row = c >> 2;
      int kc = (c & 3) ^ ((c >> 3) & 3);
      int rb = n0 + row; rb = rb < N ? rb : N - 1;
      const u16* gb = Bt + (size_t)rb * K + k0 + kc * 8;
      __builtin_amdgcn_global_load_lds(
          (const __attribute__((address_space(1))) void*)gb,
          (__attribute__((address_space(3))) void*)(Bs + buf * 4096 + c * 8), 16, 0, 0);
    }
  };

  // swizzled read slot: ((row>>1)&3) == ((lm>>1)&3) for row = 16*m + lm
  int kidx = (lk ^ ((lm >> 1) & 3)) * 8;

  stage(0, 0);
  __syncthreads();
  for (int kt = 0; kt < NK; ++kt) {
    int buf = kt & 1;
    if (kt + 1 < NK) stage(buf ^ 1, kt + 1);
    short8 af[MI], bf[4];
#pragma unroll
    for (int i = 0; i < MI; ++i)
      af[i] = *reinterpret_cast<const short8*>(As + buf * ABUF + (wm + i * 16 + lm) * 32 + kidx);
#pragma unroll
    for (int j = 0; j < 4; ++j)
      bf[j] = *reinterpret_cast<const short8*>(Bs + buf * 4096 + (wn + j * 16 + lm) * 32 + kidx);
#pragma unroll
    for (int i = 0; i < MI; ++i)
#pragma unroll
      for (int j = 0; j < 4; ++j)
        acc[i][j] = __builtin_amdgcn_mfma_f32_16x16x32_bf16(af[i], bf[j], acc[i][j], 0, 0, 0);
    __syncthreads();
  }

  // epilogue. C/D frag layout: row = i*16 + lk*4 + qq, col = j*16 + lm.
  if (!OUTF32) {
    u16* ep = smem + w * (BM / 2) * 64;
#pragma unroll
    for (int j = 0; j < 4; ++j) {
      int col = n0 + wn + j * 16 + lm;
      float bv = (ACT > 0) ? bias[col < N ? col : N - 1] : 0.0f;
#pragma unroll
      for (int i = 0; i < MI; ++i)
#pragma unroll
        for (int qq = 0; qq < 4; ++qq) {
          float v = acc[i][j][qq];
          if (ACT > 0) { v += bv; v = eluf(v); }
          if (ACT == 2) v = eluf(v);
          ep[(i * 16 + lk * 4 + qq) * 64 + j * 16 + lm] = f2b(v);
        }
    }
    __syncthreads();
    u16* op = (u16*)outp;
#pragma unroll
    for (int u = 0; u < BM / 16; ++u) {
      int rrow = m0 + wm + u * 8 + (l >> 3);
      int col = n0 + wn + (l & 7) * 8;
      if (rrow < M && col < N)
        *reinterpret_cast<short8*>(op + (size_t)rrow * N + col) =
            *reinterpret_cast<const short8*>(ep + u * 512 + l * 8);
    }
  } else {
    float* op = (float*)outp;
#pragma unroll
    for (int j = 0; j < 4; ++j) {
      int col = n0 + wn + j * 16 + lm;
      if (col >= N) continue;
      float bv = (ACT > 0) ? bias[col] : 0.0f;
#pragma unroll
      for (int i = 0; i < MI; ++i) {
        int rb = m0 + wm + i * 16 + lk * 4;
#pragma unroll
        for (int qq = 0; qq < 4; ++qq) {
          int rr = rb + qq;
          if (rr >= M) continue;
          float v = acc[i][j][qq];
          if (ACT > 0) { v += bv; v = eluf(v); }
          if (ACT == 2) v = eluf(v);
          op[(size_t)rr * N + col] = v;
        }
      }
    }
  }
}

extern "C" void kernel_launch(void* const* d_in, const int* in_sizes, int n_in,
                              void* d_out, int out_size, void* d_ws, size_t ws_size,
                              hipStream_t stream) {
  const float* features = (const float*)d_in[0];
  const int* eidx = (const int*)d_in[1];
  const float* w1a = (const float*)d_in[2];
  const float* b1a = (const float*)d_in[3];
  const float* w1b = (const float*)d_in[4];
  const float* b1b = (const float*)d_in[5];
  const float* w2a = (const float*)d_in[6];
  const float* b2a = (const float*)d_in[7];
  const float* w2b = (const float*)d_in[8];
  const float* b2b = (const float*)d_in[9];
  const float* w3a = (const float*)d_in[10];
  const float* b3a = (const float*)d_in[11];
  const float* w3b = (const float*)d_in[12];
  const float* b3b = (const float*)d_in[13];
  const float* wr = (const float*)d_in[14];
  const float* br = (const float*)d_in[15];

  char* ws = (char*)d_ws;
  u16* bufA = (u16*)(ws);                  // 20000*640 bf16 = 25.6e6 B
  u16* bufB = (u16*)(ws + 25600000);       // same
  u16* wrt = (u16*)(ws + 51200000);        // transposed bf16 weights
  u16* w1at = wrt + 256 * 256;
  u16* w1bt = w1at + 640 * 256;
  u16* w2at = w1bt + 640 * 640;
  u16* w2bt = w2at + 320 * 640;
  u16* w3at = w2bt + 320 * 320;
  u16* w3bt = w3at + 256 * 320;
  int* row_start = (int*)(ws + 53387264);  // NN+1 ints
  int* cursor = row_start + 20004;
  int* csr_src = cursor + NN;

  const int* esrc = eidx;
  const int* edst = eidx + NE;

  // CSR build (reused by all 3 layers)
  hipMemsetAsync(cursor, 0, NN * sizeof(int), stream);
  k_hist<<<(NE + 255) / 256, 256, 0, stream>>>(edst, cursor, NE);
  k_scan<<<1, 1024, 0, stream>>>(cursor, row_start, NN);
  hipMemcpyAsync(cursor, row_start, NN * sizeof(int), hipMemcpyDeviceToDevice, stream);
  k_scatter<<<(NE + 255) / 256, 256, 0, stream>>>(esrc, edst, cursor, csr_src, NE);

  // features -> bf16 (bufA), weights -> bf16 transposed
  k_f2b<<<(NN * 256 / 4 + 255) / 256, 256, 0, stream>>>(features, bufA, NN * 256);
  k_wt<<<(256 * 256 + 255) / 256, 256, 0, stream>>>(wr, wrt, 256, 256);
  k_wt<<<(256 * 640 + 255) / 256, 256, 0, stream>>>(w1a, w1at, 256, 640);
  k_wt<<<(640 * 640 + 255) / 256, 256, 0, stream>>>(w1b, w1bt, 640, 640);
  k_wt<<<(640 * 320 + 255) / 256, 256, 0, stream>>>(w2a, w2at, 640, 320);
  k_wt<<<(320 * 320 + 255) / 256, 256, 0, stream>>>(w2b, w2bt, 320, 320);
  k_wt<<<(320 * 256 + 255) / 256, 256, 0, stream>>>(w3a, w3at, 320, 256);
  k_wt<<<(256 * 256 + 255) / 256, 256, 0, stream>>>(w3b, w3bt, 256, 256);

  float* out_x = (float*)d_out;
  float* out_res = (float*)d_out + (size_t)NN * 256;

  // res = elu(X @ Wr + br)
  k_gemm<64, 256, 256, 1, true><<<dim3(313 * 2), 256, 0, stream>>>(bufA, wrt, br, out_res, NN);
  // L1: h0 = X + agg(X)  (aggregate in 256-dim, before the up-projection)
  k_agg<256, 0><<<2500, 256, 0, stream>>>(bufA, row_start, csr_src, nullptr, bufB);
  // t1 = elu(h0 @ w1a + b1a)
  k_gemm<128, 256, 640, 1, false><<<dim3(157 * 5), 256, 0, stream>>>(bufB, w1at, b1a, bufA, NN);
  // x1 = elu(elu(t1 @ w1b + b1b))
  k_gemm<128, 640, 640, 2, false><<<dim3(157 * 5), 256, 0, stream>>>(bufA, w1bt, b1b, bufB, NN);
  // L2 (agg commuted past w2a): y2 = x1 @ w2a   [320-dim, no bias/act]
  k_gemm<64, 640, 320, 0, false><<<dim3(313 * 3), 256, 0, stream>>>(bufB, w2at, nullptr, bufA, NN);
  // t2 = elu(y2 + agg(y2) + b2a)
  k_agg<320, 1><<<3125, 256, 0, stream>>>(bufA, row_start, csr_src, b2a, bufB);
  // x2 = elu(elu(t2 @ w2b + b2b))
  k_gemm<64, 320, 320, 2, false><<<dim3(313 * 3), 256, 0, stream>>>(bufB, w2bt, b2b, bufA, NN);
  // L3 (agg commuted past w3a): y3 = x2 @ w3a   [256-dim]
  k_gemm<64, 320, 256, 0, false><<<dim3(313 * 2), 256, 0, stream>>>(bufA, w3at, nullptr, bufB, NN);
  // t3 = elu(y3 + agg(y3) + b3a)
  k_agg<256, 1><<<2500, 256, 0, stream>>>(bufB, row_start, csr_src, b3a, bufA);
  // x = elu(t3 @ w3b + b3b)
  k_gemm<64, 256, 256, 1, true><<<dim3(313 * 2), 256, 0, stream>>>(bufA, w3bt, b3b, out_x, NN);
}

// Round 4
// 302.240 us; speedup vs baseline: 1.6194x; 1.1615x over previous
//
#include <hip/hip_runtime.h>
#include <cstdint>
#include <cstddef>

#define NN 20000
#define NE 320000

typedef short short8 __attribute__((ext_vector_type(8)));
typedef float f32x4 __attribute__((ext_vector_type(4)));
typedef unsigned short u16;

__device__ __forceinline__ float b2f(u16 u) {
  union { unsigned int i; float f; } z; z.i = ((unsigned int)u) << 16; return z.f;
}
__device__ __forceinline__ u16 f2b(float f) {
  union { float f; unsigned int i; } z; z.f = f;
  unsigned int r = z.i + 0x7fffu + ((z.i >> 16) & 1u);
  return (u16)(r >> 16);
}
// fast ELU: v_exp_f32-based, not libm expm1f (which is ~40 branchy VALU ops)
__device__ __forceinline__ float eluf(float v) {
  return v > 0.0f ? v : __expf(v) - 1.0f;
}

// ---------------- fp32 -> bf16 convert (features) ----------------
__global__ __launch_bounds__(256) void k_f2b(const float* __restrict__ in,
                                             u16* __restrict__ out, int n) {
  int i = (blockIdx.x * 256 + threadIdx.x) * 4;
  if (i >= n) return;
  float4 v = *reinterpret_cast<const float4*>(in + i);
  ushort4 o;
  o.x = f2b(v.x); o.y = f2b(v.y); o.z = f2b(v.z); o.w = f2b(v.w);
  *reinterpret_cast<ushort4*>(out + i) = o;
}

// ---------------- weight transpose + convert: W[K][N] -> Wt[N][K] bf16 ------
__global__ __launch_bounds__(256) void k_wt(const float* __restrict__ W,
                                            u16* __restrict__ Wt, int Kd, int Nd) {
  int idx = blockIdx.x * 256 + threadIdx.x;
  if (idx >= Kd * Nd) return;
  int n = idx / Kd, k = idx - n * Kd;
  Wt[idx] = f2b(W[(size_t)k * Nd + n]);
}

// ---------------- CSR build ----------------
__global__ __launch_bounds__(256) void k_hist(const int* __restrict__ dst,
                                              int* __restrict__ counts, int ne) {
  int i = blockIdx.x * 256 + threadIdx.x;
  if (i < ne) atomicAdd(&counts[dst[i]], 1);
}

__global__ __launch_bounds__(1024) void k_scan(const int* __restrict__ counts,
                                               int* __restrict__ rs, int n) {
  __shared__ int wsum[16];
  __shared__ int carry_s;
  int t = threadIdx.x;
  int l = t & 63, w = t >> 6;
  if (t == 0) carry_s = 0;
  __syncthreads();
  for (int base = 0; base < n; base += 1024) {
    int i = base + t;
    int v = (i < n) ? counts[i] : 0;
    int incl = v;
#pragma unroll
    for (int off = 1; off < 64; off <<= 1) {
      int u = __shfl_up(incl, off, 64);
      if (l >= off) incl += u;
    }
    if (l == 63) wsum[w] = incl;
    __syncthreads();
    int carry = carry_s;
    int wpre = 0;
    for (int k2 = 0; k2 < w; ++k2) wpre += wsum[k2];
    if (i < n) rs[i] = carry + wpre + incl - v;
    int tot = 0;
    if (t == 0) {
      for (int k2 = 0; k2 < 16; ++k2) tot += wsum[k2];
    }
    __syncthreads();
    if (t == 0) carry_s = carry + tot;
    __syncthreads();
  }
  if (threadIdx.x == 0) rs[n] = carry_s;
}

__global__ __launch_bounds__(256) void k_scatter(const int* __restrict__ src,
                                                 const int* __restrict__ dst,
                                                 int* __restrict__ cursor,
                                                 int* __restrict__ csr_src, int ne) {
  int i = blockIdx.x * 256 + threadIdx.x;
  if (i >= ne) return;
  int d = dst[i];
  int p = atomicAdd(&cursor[d], 1);
  csr_src[p] = src[i];
}

// ---- aggregation: h[n] = f(x[n] + sum_{s in in(n)} x[s]), flat (node,chunk) -
// ACT=0: f = identity (no bias).  ACT=1: f = elu(v + bias).
template <int D, int ACT>
__global__ __launch_bounds__(256) void k_agg(const u16* __restrict__ x,
                                             const int* __restrict__ rs,
                                             const int* __restrict__ cs,
                                             const float* __restrict__ bias,
                                             u16* __restrict__ h) {
  constexpr int NC = D / 8;  // 16B chunks per row
  int tid = blockIdx.x * 256 + threadIdx.x;
  if (tid >= NN * NC) return;
  int node = tid / NC;
  int c = tid - node * NC;
  const u16* xp = x + (size_t)c * 8;
  float acc[8];
  {
    short8 v = *reinterpret_cast<const short8*>(xp + (size_t)node * D);
#pragma unroll
    for (int q = 0; q < 8; ++q) acc[q] = b2f((u16)v[q]);
  }
  int e0 = rs[node], e1 = rs[node + 1];
  int e = e0;
  // 4-wide unroll: 4 independent index loads + 4 independent gathers in flight
  for (; e + 4 <= e1; e += 4) {
    int s0 = cs[e], s1 = cs[e + 1], s2 = cs[e + 2], s3 = cs[e + 3];
    short8 v0 = *reinterpret_cast<const short8*>(xp + (size_t)s0 * D);
    short8 v1 = *reinterpret_cast<const short8*>(xp + (size_t)s1 * D);
    short8 v2 = *reinterpret_cast<const short8*>(xp + (size_t)s2 * D);
    short8 v3 = *reinterpret_cast<const short8*>(xp + (size_t)s3 * D);
#pragma unroll
    for (int q = 0; q < 8; ++q)
      acc[q] += (b2f((u16)v0[q]) + b2f((u16)v1[q])) + (b2f((u16)v2[q]) + b2f((u16)v3[q]));
  }
  for (; e < e1; ++e) {
    int s = cs[e];
    short8 v = *reinterpret_cast<const short8*>(xp + (size_t)s * D);
#pragma unroll
    for (int q = 0; q < 8; ++q) acc[q] += b2f((u16)v[q]);
  }
  if (ACT == 1) {
    float4 b0 = *reinterpret_cast<const float4*>(bias + c * 8);
    float4 b1 = *reinterpret_cast<const float4*>(bias + c * 8 + 4);
    acc[0] = eluf(acc[0] + b0.x); acc[1] = eluf(acc[1] + b0.y);
    acc[2] = eluf(acc[2] + b0.z); acc[3] = eluf(acc[3] + b0.w);
    acc[4] = eluf(acc[4] + b1.x); acc[5] = eluf(acc[5] + b1.y);
    acc[6] = eluf(acc[6] + b1.z); acc[7] = eluf(acc[7] + b1.w);
  }
  short8 o;
#pragma unroll
  for (int q = 0; q < 8; ++q) o[q] = (short)f2b(acc[q]);
  *reinterpret_cast<short8*>(h + (size_t)node * D + (size_t)c * 8) = o;
}

// ---------------- GEMM: C = act(A[M][K] @ B[K][N] + bias) ----------------
// A bf16 [M][K], Bt bf16 [N][K]. BMx128 tile, BK=32, 2-deep prefetch ring with
// counted vmcnt + raw s_barrier (T3/T4), 4 waves (2x2), 16x16x32 bf16 MFMA,
// swizzled LDS, XCD-chunked grid.
// ACT: 0 = none (no bias), 1 = elu(v+bias), 2 = elu(elu(v+bias)).
template <int BM, int K, int N, int ACT, bool OUTF32>
__global__ __launch_bounds__(256) void k_gemm(const u16* __restrict__ A,
                                              const u16* __restrict__ Bt,
                                              const float* __restrict__ bias,
                                              void* __restrict__ outp, int M) {
  constexpr int NBY = (N + 127) / 128;
  constexpr int NK = K / 32;
  constexpr int ABUF = BM * 32;       // u16 per A LDS buffer
  constexpr int MI = BM / 32;         // acc i-extent per wave (2 or 4)
  constexpr int LPT = BM / 64 + 2;    // global_load_lds per thread per stage
  __shared__ __align__(16) u16 smem[2 * ABUF + 8192];
  u16* As = smem;
  u16* Bs = smem + 2 * ABUF;
  int t = threadIdx.x;
  int l = t & 63, w = t >> 6;
  int lm = l & 15, lk = l >> 4;

  // bijective XCD-chunked swizzle (m204)
  int nb = gridDim.x;
  int q8 = nb >> 3, r8 = nb & 7;
  int orig = blockIdx.x;
  int xcd = orig & 7, idx = orig >> 3;
  int wg = (xcd < r8 ? xcd * (q8 + 1) : r8 * (q8 + 1) + (xcd - r8) * q8) + idx;
  int m0 = (wg / NBY) * BM;
  int n0 = (wg % NBY) * 128;
  int wm = (w >> 1) * (BM / 2), wn = (w & 1) * 64;

  f32x4 acc[MI][4];
#pragma unroll
  for (int i = 0; i < MI; ++i)
#pragma unroll
    for (int j = 0; j < 4; ++j)
#pragma unroll
      for (int qq = 0; qq < 4; ++qq) acc[i][j][qq] = 0.0f;

  // stage one K-slab; k-chunk pre-swizzled in the GLOBAL source (rule #21)
  auto stage = [&](int buf, int kt) {
    int k0 = kt * 32;
#pragma unroll
    for (int it = 0; it < BM / 64; ++it) {  // A: BM*32 u16 / (256 thr * 8)
      int c = it * 256 + t;
      int row = c >> 2;
      int kc = (c & 3) ^ ((c >> 3) & 3);
      int ra = m0 + row; ra = ra < M ? ra : M - 1;
      const u16* ga = A + (size_t)ra * K + k0 + kc * 8;
      __builtin_amdgcn_global_load_lds(
          (const __attribute__((address_space(1))) void*)ga,
          (__attribute__((address_space(3))) void*)(As + buf * ABUF + c * 8), 16, 0, 0);
    }
#pragma unroll
    for (int it = 0; it < 2; ++it) {        // B: 128*32 u16
      int c = it * 256 + t;
      int row = c >> 2;
      int kc = (c & 3) ^ ((c >> 3) & 3);
      int rb = n0 + row; rb = rb < N ? rb : N - 1;
      const u16* gb = Bt + (size_t)rb * K + k0 + kc * 8;
      __builtin_amdgcn_global_load_lds(
          (const __attribute__((address_space(1))) void*)gb,
          (__attribute__((address_space(3))) void*)(Bs + buf * 4096 + c * 8), 16, 0, 0);
    }
  };

  // swizzled read slot: ((row>>1)&3) == ((lm>>1)&3) for row = 16*m + lm
  int kidx = (lk ^ ((lm >> 1) & 3)) * 8;

  // 2-deep prefetch ring, counted vmcnt (never 0 in steady state), raw barriers.
  stage(0, 0);
  stage(1, 1);
  for (int kt = 0; kt < NK; ++kt) {
    int buf = kt & 1;
    // wait for stage(kt) only; stage(kt+1)'s LPT loads stay in flight
    if (kt + 1 < NK)
      asm volatile("s_waitcnt vmcnt(%0)" ::"n"(LPT) : "memory");
    else
      asm volatile("s_waitcnt vmcnt(0)" ::: "memory");
    __builtin_amdgcn_s_barrier();          // buf[kt&1] now complete for all waves
    asm volatile("" ::: "memory");         // pin ds_reads below the barrier
    short8 af[MI], bf[4];
#pragma unroll
    for (int i = 0; i < MI; ++i)
      af[i] = *reinterpret_cast<const short8*>(As + buf * ABUF + (wm + i * 16 + lm) * 32 + kidx);
#pragma unroll
    for (int j = 0; j < 4; ++j)
      bf[j] = *reinterpret_cast<const short8*>(Bs + buf * 4096 + (wn + j * 16 + lm) * 32 + kidx);
#pragma unroll
    for (int i = 0; i < MI; ++i)
#pragma unroll
      for (int j = 0; j < 4; ++j)
        acc[i][j] = __builtin_amdgcn_mfma_f32_16x16x32_bf16(af[i], bf[j], acc[i][j], 0, 0, 0);
    // drain this wave's ds_reads, then barrier: all waves done READING buf
    asm volatile("s_waitcnt lgkmcnt(0)" ::: "memory");
    __builtin_amdgcn_s_barrier();
    asm volatile("" ::: "memory");         // pin next stage below the barrier
    if (kt + 2 < NK) stage(buf, kt + 2);   // overwrite the buf just consumed
  }

  // epilogue. C/D frag layout: row = i*16 + lk*4 + qq, col = j*16 + lm.
  if (!OUTF32) {
    u16* ep = smem + w * (BM / 2) * 64;
#pragma unroll
    for (int j = 0; j < 4; ++j) {
      int col = n0 + wn + j * 16 + lm;
      float bv = (ACT > 0) ? bias[col < N ? col : N - 1] : 0.0f;
#pragma unroll
      for (int i = 0; i < MI; ++i)
#pragma unroll
        for (int qq = 0; qq < 4; ++qq) {
          float v = acc[i][j][qq];
          if (ACT > 0) { v += bv; v = eluf(v); }
          if (ACT == 2) v = eluf(v);
          ep[(i * 16 + lk * 4 + qq) * 64 + j * 16 + lm] = f2b(v);
        }
    }
    __syncthreads();
    u16* op = (u16*)outp;
#pragma unroll
    for (int u = 0; u < BM / 16; ++u) {
      int rrow = m0 + wm + u * 8 + (l >> 3);
      int col = n0 + wn + (l & 7) * 8;
      if (rrow < M && col < N)
        *reinterpret_cast<short8*>(op + (size_t)rrow * N + col) =
            *reinterpret_cast<const short8*>(ep + u * 512 + l * 8);
    }
  } else {
    float* op = (float*)outp;
#pragma unroll
    for (int j = 0; j < 4; ++j) {
      int col = n0 + wn + j * 16 + lm;
      if (col >= N) continue;
      float bv = (ACT > 0) ? bias[col] : 0.0f;
#pragma unroll
      for (int i = 0; i < MI; ++i) {
        int rb = m0 + wm + i * 16 + lk * 4;
#pragma unroll
        for (int qq = 0; qq < 4; ++qq) {
          int rr = rb + qq;
          if (rr >= M) continue;
          float v = acc[i][j][qq];
          if (ACT > 0) { v += bv; v = eluf(v); }
          if (ACT == 2) v = eluf(v);
          op[(size_t)rr * N + col] = v;
        }
      }
    }
  }
}

extern "C" void kernel_launch(void* const* d_in, const int* in_sizes, int n_in,
                              void* d_out, int out_size, void* d_ws, size_t ws_size,
                              hipStream_t stream) {
  const float* features = (const float*)d_in[0];
  const int* eidx = (const int*)d_in[1];
  const float* w1a = (const float*)d_in[2];
  const float* b1a = (const float*)d_in[3];
  const float* w1b = (const float*)d_in[4];
  const float* b1b = (const float*)d_in[5];
  const float* w2a = (const float*)d_in[6];
  const float* b2a = (const float*)d_in[7];
  const float* w2b = (const float*)d_in[8];
  const float* b2b = (const float*)d_in[9];
  const float* w3a = (const float*)d_in[10];
  const float* b3a = (const float*)d_in[11];
  const float* w3b = (const float*)d_in[12];
  const float* b3b = (const float*)d_in[13];
  const float* wr = (const float*)d_in[14];
  const float* br = (const float*)d_in[15];

  char* ws = (char*)d_ws;
  u16* bufA = (u16*)(ws);                  // 20000*640 bf16 = 25.6e6 B
  u16* bufB = (u16*)(ws + 25600000);       // same
  u16* wrt = (u16*)(ws + 51200000);        // transposed bf16 weights
  u16* w1at = wrt + 256 * 256;
  u16* w1bt = w1at + 640 * 256;
  u16* w2at = w1bt + 640 * 640;
  u16* w2bt = w2at + 320 * 640;
  u16* w3at = w2bt + 320 * 320;
  u16* w3bt = w3at + 256 * 320;
  int* row_start = (int*)(ws + 53387264);  // NN+1 ints
  int* cursor = row_start + 20004;
  int* csr_src = cursor + NN;

  const int* esrc = eidx;
  const int* edst = eidx + NE;

  // CSR build (reused by all 3 layers)
  hipMemsetAsync(cursor, 0, NN * sizeof(int), stream);
  k_hist<<<(NE + 255) / 256, 256, 0, stream>>>(edst, cursor, NE);
  k_scan<<<1, 1024, 0, stream>>>(cursor, row_start, NN);
  hipMemcpyAsync(cursor, row_start, NN * sizeof(int), hipMemcpyDeviceToDevice, stream);
  k_scatter<<<(NE + 255) / 256, 256, 0, stream>>>(esrc, edst, cursor, csr_src, NE);

  // features -> bf16 (bufA), weights -> bf16 transposed
  k_f2b<<<(NN * 256 / 4 + 255) / 256, 256, 0, stream>>>(features, bufA, NN * 256);
  k_wt<<<(256 * 256 + 255) / 256, 256, 0, stream>>>(wr, wrt, 256, 256);
  k_wt<<<(256 * 640 + 255) / 256, 256, 0, stream>>>(w1a, w1at, 256, 640);
  k_wt<<<(640 * 640 + 255) / 256, 256, 0, stream>>>(w1b, w1bt, 640, 640);
  k_wt<<<(640 * 320 + 255) / 256, 256, 0, stream>>>(w2a, w2at, 640, 320);
  k_wt<<<(320 * 320 + 255) / 256, 256, 0, stream>>>(w2b, w2bt, 320, 320);
  k_wt<<<(320 * 256 + 255) / 256, 256, 0, stream>>>(w3a, w3at, 320, 256);
  k_wt<<<(256 * 256 + 255) / 256, 256, 0, stream>>>(w3b, w3bt, 256, 256);

  float* out_x = (float*)d_out;
  float* out_res = (float*)d_out + (size_t)NN * 256;

  // res = elu(X @ Wr + br)
  k_gemm<64, 256, 256, 1, true><<<dim3(313 * 2), 256, 0, stream>>>(bufA, wrt, br, out_res, NN);
  // L1: h0 = X + agg(X)  (aggregate in 256-dim, before the up-projection)
  k_agg<256, 0><<<2500, 256, 0, stream>>>(bufA, row_start, csr_src, nullptr, bufB);
  // t1 = elu(h0 @ w1a + b1a)
  k_gemm<64, 256, 640, 1, false><<<dim3(313 * 5), 256, 0, stream>>>(bufB, w1at, b1a, bufA, NN);
  // x1 = elu(elu(t1 @ w1b + b1b))
  k_gemm<64, 640, 640, 2, false><<<dim3(313 * 5), 256, 0, stream>>>(bufA, w1bt, b1b, bufB, NN);
  // L2 (agg commuted past w2a): y2 = x1 @ w2a   [320-dim, no bias/act]
  k_gemm<64, 640, 320, 0, false><<<dim3(313 * 3), 256, 0, stream>>>(bufB, w2at, nullptr, bufA, NN);
  // t2 = elu(y2 + agg(y2) + b2a)
  k_agg<320, 1><<<3125, 256, 0, stream>>>(bufA, row_start, csr_src, b2a, bufB);
  // x2 = elu(elu(t2 @ w2b + b2b))
  k_gemm<64, 320, 320, 2, false><<<dim3(313 * 3), 256, 0, stream>>>(bufB, w2bt, b2b, bufA, NN);
  // L3 (agg commuted past w3a): y3 = x2 @ w3a   [256-dim]
  k_gemm<64, 320, 256, 0, false><<<dim3(313 * 2), 256, 0, stream>>>(bufA, w3at, nullptr, bufB, NN);
  // t3 = elu(y3 + agg(y3) + b3a)
  k_agg<256, 1><<<2500, 256, 0, stream>>>(bufB, row_start, csr_src, b3a, bufA);
  // x = elu(t3 @ w3b + b3b)
  k_gemm<64, 256, 256, 1, true><<<dim3(313 * 2), 256, 0, stream>>>(bufA, w3bt, b3b, out_x, NN);
}

// Round 5
// 269.404 us; speedup vs baseline: 1.8168x; 1.1219x over previous
//
#include <hip/hip_runtime.h>
#include <cstdint>
#include <cstddef>

#define NN 20000
#define NE 320000

typedef short short8 __attribute__((ext_vector_type(8)));
typedef float f32x4 __attribute__((ext_vector_type(4)));
typedef unsigned short u16;

__device__ __forceinline__ float b2f(u16 u) {
  union { unsigned int i; float f; } z; z.i = ((unsigned int)u) << 16; return z.f;
}
__device__ __forceinline__ u16 f2b(float f) {
  union { float f; unsigned int i; } z; z.f = f;
  unsigned int r = z.i + 0x7fffu + ((z.i >> 16) & 1u);
  return (u16)(r >> 16);
}
// fast ELU: v_exp_f32-based, not libm expm1f
__device__ __forceinline__ float eluf(float v) {
  return v > 0.0f ? v : __expf(v) - 1.0f;
}

// ------- fused prep: features f2b (4 elems/thread) + 7 weight transposes ----
// virtual thread space: [0,1280000) f2b ; then per-weight 1 elem/thread.
__global__ __launch_bounds__(256) void k_prep(
    const float* __restrict__ features, u16* __restrict__ xbf,
    const float* __restrict__ wr, const float* __restrict__ w1a,
    const float* __restrict__ w1b, const float* __restrict__ w2a,
    const float* __restrict__ w2b, const float* __restrict__ w3a,
    const float* __restrict__ w3b,
    u16* __restrict__ wrt, u16* __restrict__ w1at, u16* __restrict__ w1bt,
    u16* __restrict__ w2at, u16* __restrict__ w2bt, u16* __restrict__ w3at,
    u16* __restrict__ w3bt) {
  int tid = blockIdx.x * 256 + threadIdx.x;
  if (tid < 1280000) {
    int i = tid * 4;
    float4 v = *reinterpret_cast<const float4*>(features + i);
    ushort4 o;
    o.x = f2b(v.x); o.y = f2b(v.y); o.z = f2b(v.z); o.w = f2b(v.w);
    *reinterpret_cast<ushort4*>(xbf + i) = o;
    return;
  }
  int r = tid - 1280000;
  const float* Ws[7] = {wr, w1a, w1b, w2a, w2b, w3a, w3b};
  u16* Wts[7] = {wrt, w1at, w1bt, w2at, w2bt, w3at, w3bt};
  const int Kd[7] = {256, 256, 640, 640, 320, 320, 256};
  const int Nd[7] = {256, 640, 640, 320, 320, 256, 256};
  const int cnt[7] = {65536, 163840, 409600, 204800, 102400, 81920, 65536};
#pragma unroll
  for (int j = 0; j < 7; ++j) {
    if (r < cnt[j]) {
      int n = r / Kd[j], k = r - n * Kd[j];
      Wts[j][r] = f2b(Ws[j][(size_t)k * Nd[j] + n]);
      return;
    }
    r -= cnt[j];
  }
}

// ---------------- CSR build ----------------
__global__ __launch_bounds__(256) void k_hist(const int* __restrict__ dst,
                                              int* __restrict__ counts, int ne) {
  int i = blockIdx.x * 256 + threadIdx.x;
  if (i < ne) atomicAdd(&counts[dst[i]], 1);
}

// x4-vectorized single-block scan; writes exclusive prefix to BOTH rs and cur.
__global__ __launch_bounds__(1024) void k_scan(const int* __restrict__ counts,
                                               int* __restrict__ rs,
                                               int* __restrict__ cur) {
  __shared__ int wsum[16];
  __shared__ int carry_s;
  int t = threadIdx.x;
  int l = t & 63, w = t >> 6;
  if (t == 0) carry_s = 0;
  __syncthreads();
  for (int base = 0; base < NN; base += 4096) {
    int idx = base + t * 4;
    int4 v = {0, 0, 0, 0};
    if (idx < NN) v = *reinterpret_cast<const int4*>(counts + idx);
    int p0 = v.x, p1 = p0 + v.y, p2 = p1 + v.z, p3 = p2 + v.w;
    int incl = p3;
#pragma unroll
    for (int off = 1; off < 64; off <<= 1) {
      int u = __shfl_up(incl, off, 64);
      if (l >= off) incl += u;
    }
    if (l == 63) wsum[w] = incl;
    __syncthreads();  // (A) wsum ready
    int carry = carry_s;
    int wpre = 0;
    for (int k2 = 0; k2 < w; ++k2) wpre += wsum[k2];
    int tot = 0;
    if (t == 0)
      for (int k2 = 0; k2 < 16; ++k2) tot += wsum[k2];
    int ex = carry + wpre + incl - p3;
    if (idx < NN) {
      int4 o;
      o.x = ex; o.y = ex + p0; o.z = ex + p1; o.w = ex + p2;
      *reinterpret_cast<int4*>(rs + idx) = o;
      *reinterpret_cast<int4*>(cur + idx) = o;
    }
    __syncthreads();  // (B) all reads of wsum/carry_s done
    if (t == 0) carry_s = carry + tot;
    __syncthreads();  // (C) carry_s updated
  }
  if (t == 0) rs[NN] = carry_s;
}

__global__ __launch_bounds__(256) void k_scatter(const int* __restrict__ src,
                                                 const int* __restrict__ dst,
                                                 int* __restrict__ cursor,
                                                 int* __restrict__ csr_src, int ne) {
  int i = blockIdx.x * 256 + threadIdx.x;
  if (i >= ne) return;
  int d = dst[i];
  int p = atomicAdd(&cursor[d], 1);
  csr_src[p] = src[i];
}

// ---- aggregation: h[n] = f(x[n] + sum_{s in in(n)} x[s]), flat (node,chunk) -
// ACT=0: f = identity (no bias).  ACT=1: f = elu(v + bias).
template <int D, int ACT>
__global__ __launch_bounds__(256) void k_agg(const u16* __restrict__ x,
                                             const int* __restrict__ rs,
                                             const int* __restrict__ cs,
                                             const float* __restrict__ bias,
                                             u16* __restrict__ h) {
  constexpr int NC = D / 8;  // 16B chunks per row
  int tid = blockIdx.x * 256 + threadIdx.x;
  if (tid >= NN * NC) return;
  int node = tid / NC;
  int c = tid - node * NC;
  const u16* xp = x + (size_t)c * 8;
  float acc[8];
  {
    short8 v = *reinterpret_cast<const short8*>(xp + (size_t)node * D);
#pragma unroll
    for (int q = 0; q < 8; ++q) acc[q] = b2f((u16)v[q]);
  }
  int e0 = rs[node], e1 = rs[node + 1];
  int e = e0;
  // 8-wide unroll: 8 independent index loads + 8 independent gathers in flight
  for (; e + 8 <= e1; e += 8) {
    int s[8];
#pragma unroll
    for (int u = 0; u < 8; ++u) s[u] = cs[e + u];
    short8 v[8];
#pragma unroll
    for (int u = 0; u < 8; ++u)
      v[u] = *reinterpret_cast<const short8*>(xp + (size_t)s[u] * D);
#pragma unroll
    for (int q = 0; q < 8; ++q) {
      float a0 = b2f((u16)v[0][q]) + b2f((u16)v[1][q]);
      float a1 = b2f((u16)v[2][q]) + b2f((u16)v[3][q]);
      float a2 = b2f((u16)v[4][q]) + b2f((u16)v[5][q]);
      float a3 = b2f((u16)v[6][q]) + b2f((u16)v[7][q]);
      acc[q] += (a0 + a1) + (a2 + a3);
    }
  }
  for (; e + 4 <= e1; e += 4) {
    int s0 = cs[e], s1 = cs[e + 1], s2 = cs[e + 2], s3 = cs[e + 3];
    short8 v0 = *reinterpret_cast<const short8*>(xp + (size_t)s0 * D);
    short8 v1 = *reinterpret_cast<const short8*>(xp + (size_t)s1 * D);
    short8 v2 = *reinterpret_cast<const short8*>(xp + (size_t)s2 * D);
    short8 v3 = *reinterpret_cast<const short8*>(xp + (size_t)s3 * D);
#pragma unroll
    for (int q = 0; q < 8; ++q)
      acc[q] += (b2f((u16)v0[q]) + b2f((u16)v1[q])) + (b2f((u16)v2[q]) + b2f((u16)v3[q]));
  }
  for (; e < e1; ++e) {
    int s = cs[e];
    short8 v = *reinterpret_cast<const short8*>(xp + (size_t)s * D);
#pragma unroll
    for (int q = 0; q < 8; ++q) acc[q] += b2f((u16)v[q]);
  }
  if (ACT == 1) {
    float4 b0 = *reinterpret_cast<const float4*>(bias + c * 8);
    float4 b1 = *reinterpret_cast<const float4*>(bias + c * 8 + 4);
    acc[0] = eluf(acc[0] + b0.x); acc[1] = eluf(acc[1] + b0.y);
    acc[2] = eluf(acc[2] + b0.z); acc[3] = eluf(acc[3] + b0.w);
    acc[4] = eluf(acc[4] + b1.x); acc[5] = eluf(acc[5] + b1.y);
    acc[6] = eluf(acc[6] + b1.z); acc[7] = eluf(acc[7] + b1.w);
  }
  short8 o;
#pragma unroll
  for (int q = 0; q < 8; ++q) o[q] = (short)f2b(acc[q]);
  *reinterpret_cast<short8*>(h + (size_t)node * D + (size_t)c * 8) = o;
}

// ---------------- GEMM: C = act(A[M][K] @ B[K][N] + bias) ----------------
// A bf16 [M][K], Bt bf16 [N][K]. BMx128 tile, BK=32, 3-deep prefetch ring with
// counted vmcnt + raw s_barrier (T3/T4), setprio around MFMA (T5), 4 waves
// (2x2), 16x16x32 bf16 MFMA, swizzled LDS, XCD-chunked grid.
// ACT: 0 = none (no bias), 1 = elu(v+bias), 2 = elu(elu(v+bias)).
template <int BM, int K, int N, int ACT, bool OUTF32>
__global__ __launch_bounds__(256) void k_gemm(const u16* __restrict__ A,
                                              const u16* __restrict__ Bt,
                                              const float* __restrict__ bias,
                                              void* __restrict__ outp, int M) {
  constexpr int NBY = (N + 127) / 128;
  constexpr int NK = K / 32;
  constexpr int ABUF = BM * 32;       // u16 per A LDS buffer
  constexpr int BUFSZ = ABUF + 4096;  // A + B per ring slot
  constexpr int MI = BM / 32;         // acc i-extent per wave (2 or 4)
  constexpr int LPT = BM / 64 + 2;    // global_load_lds per thread per stage
  __shared__ __align__(16) u16 smem[3 * BUFSZ];
  int t = threadIdx.x;
  int l = t & 63, w = t >> 6;
  int lm = l & 15, lk = l >> 4;

  // bijective XCD-chunked swizzle (m204)
  int nb = gridDim.x;
  int q8 = nb >> 3, r8 = nb & 7;
  int orig = blockIdx.x;
  int xcd = orig & 7, idx = orig >> 3;
  int wg = (xcd < r8 ? xcd * (q8 + 1) : r8 * (q8 + 1) + (xcd - r8) * q8) + idx;
  int m0 = (wg / NBY) * BM;
  int n0 = (wg % NBY) * 128;
  int wm = (w >> 1) * (BM / 2), wn = (w & 1) * 64;

  f32x4 acc[MI][4];
#pragma unroll
  for (int i = 0; i < MI; ++i)
#pragma unroll
    for (int j = 0; j < 4; ++j)
#pragma unroll
      for (int qq = 0; qq < 4; ++qq) acc[i][j][qq] = 0.0f;

  // stage one K-slab into ring slot; k-chunk pre-swizzled in the GLOBAL
  // source (rule #21)
  auto stage = [&](int buf, int kt) {
    int k0 = kt * 32;
    u16* As = smem + buf * BUFSZ;
    u16* Bs = As + ABUF;
#pragma unroll
    for (int it = 0; it < BM / 64; ++it) {  // A: BM*32 u16 / (256 thr * 8)
      int c = it * 256 + t;
      int row = c >> 2;
      int kc = (c & 3) ^ ((c >> 3) & 3);
      int ra = m0 + row; ra = ra < M ? ra : M - 1;
      const u16* ga = A + (size_t)ra * K + k0 + kc * 8;
      __builtin_amdgcn_global_load_lds(
          (const __attribute__((address_space(1))) void*)ga,
          (__attribute__((address_space(3))) void*)(As + c * 8), 16, 0, 0);
    }
#pragma unroll
    for (int it = 0; it < 2; ++it) {        // B: 128*32 u16
      int c = it * 256 + t;
      int row = c >> 2;
      int kc = (c & 3) ^ ((c >> 3) & 3);
      int rb = n0 + row; rb = rb < N ? rb : N - 1;
      const u16* gb = Bt + (size_t)rb * K + k0 + kc * 8;
      __builtin_amdgcn_global_load_lds(
          (const __attribute__((address_space(1))) void*)gb,
          (__attribute__((address_space(3))) void*)(Bs + c * 8), 16, 0, 0);
    }
  };

  // swizzled read slot: ((row>>1)&3) == ((lm>>1)&3) for row = 16*m + lm
  int kidx = (lk ^ ((lm >> 1) & 3)) * 8;

  // 3-deep ring: stages kt+1, kt+2 stay in flight across the consume barrier.
  stage(0, 0);
  stage(1, 1);
  stage(2, 2);
  int buf = 0;
  for (int kt = 0; kt < NK; ++kt) {
    int rem = NK - 1 - kt;
    if (rem >= 2)
      asm volatile("s_waitcnt vmcnt(%0)" ::"n"(2 * LPT) : "memory");
    else if (rem == 1)
      asm volatile("s_waitcnt vmcnt(%0)" ::"n"(LPT) : "memory");
    else
      asm volatile("s_waitcnt vmcnt(0)" ::: "memory");
    __builtin_amdgcn_s_barrier();          // ring slot kt now complete everywhere
    asm volatile("" ::: "memory");         // pin ds_reads below the barrier
    const u16* As = smem + buf * BUFSZ;
    const u16* Bs = As + ABUF;
    short8 af[MI], bf[4];
#pragma unroll
    for (int i = 0; i < MI; ++i)
      af[i] = *reinterpret_cast<const short8*>(As + (wm + i * 16 + lm) * 32 + kidx);
#pragma unroll
    for (int j = 0; j < 4; ++j)
      bf[j] = *reinterpret_cast<const short8*>(Bs + (wn + j * 16 + lm) * 32 + kidx);
    __builtin_amdgcn_s_setprio(1);
#pragma unroll
    for (int i = 0; i < MI; ++i)
#pragma unroll
      for (int j = 0; j < 4; ++j)
        acc[i][j] = __builtin_amdgcn_mfma_f32_16x16x32_bf16(af[i], bf[j], acc[i][j], 0, 0, 0);
    __builtin_amdgcn_s_setprio(0);
    // drain this wave's ds_reads, then barrier: all waves done READING slot
    asm volatile("s_waitcnt lgkmcnt(0)" ::: "memory");
    __builtin_amdgcn_s_barrier();
    asm volatile("" ::: "memory");         // pin next stage below the barrier
    if (kt + 3 < NK) stage(buf, kt + 3);   // overwrite the slot just consumed
    buf = (buf == 2) ? 0 : buf + 1;
  }

  // epilogue. C/D frag layout: row = i*16 + lk*4 + qq, col = j*16 + lm.
  if (!OUTF32) {
    u16* ep = smem + w * (BM / 2) * 64;
#pragma unroll
    for (int j = 0; j < 4; ++j) {
      int col = n0 + wn + j * 16 + lm;
      float bv = (ACT > 0) ? bias[col < N ? col : N - 1] : 0.0f;
#pragma unroll
      for (int i = 0; i < MI; ++i)
#pragma unroll
        for (int qq = 0; qq < 4; ++qq) {
          float v = acc[i][j][qq];
          if (ACT > 0) { v += bv; v = eluf(v); }
          if (ACT == 2) v = eluf(v);
          ep[(i * 16 + lk * 4 + qq) * 64 + j * 16 + lm] = f2b(v);
        }
    }
    __syncthreads();
    u16* op = (u16*)outp;
#pragma unroll
    for (int u = 0; u < BM / 16; ++u) {
      int rrow = m0 + wm + u * 8 + (l >> 3);
      int col = n0 + wn + (l & 7) * 8;
      if (rrow < M && col < N)
        *reinterpret_cast<short8*>(op + (size_t)rrow * N + col) =
            *reinterpret_cast<const short8*>(ep + u * 512 + l * 8);
    }
  } else {
    float* op = (float*)outp;
#pragma unroll
    for (int j = 0; j < 4; ++j) {
      int col = n0 + wn + j * 16 + lm;
      if (col >= N) continue;
      float bv = (ACT > 0) ? bias[col] : 0.0f;
#pragma unroll
      for (int i = 0; i < MI; ++i) {
        int rb = m0 + wm + i * 16 + lk * 4;
#pragma unroll
        for (int qq = 0; qq < 4; ++qq) {
          int rr = rb + qq;
          if (rr >= M) continue;
          float v = acc[i][j][qq];
          if (ACT > 0) { v += bv; v = eluf(v); }
          if (ACT == 2) v = eluf(v);
          op[(size_t)rr * N + col] = v;
        }
      }
    }
  }
}

extern "C" void kernel_launch(void* const* d_in, const int* in_sizes, int n_in,
                              void* d_out, int out_size, void* d_ws, size_t ws_size,
                              hipStream_t stream) {
  const float* features = (const float*)d_in[0];
  const int* eidx = (const int*)d_in[1];
  const float* w1a = (const float*)d_in[2];
  const float* b1a = (const float*)d_in[3];
  const float* w1b = (const float*)d_in[4];
  const float* b1b = (const float*)d_in[5];
  const float* w2a = (const float*)d_in[6];
  const float* b2a = (const float*)d_in[7];
  const float* w2b = (const float*)d_in[8];
  const float* b2b = (const float*)d_in[9];
  const float* w3a = (const float*)d_in[10];
  const float* b3a = (const float*)d_in[11];
  const float* w3b = (const float*)d_in[12];
  const float* b3b = (const float*)d_in[13];
  const float* wr = (const float*)d_in[14];
  const float* br = (const float*)d_in[15];

  char* ws = (char*)d_ws;
  u16* bufA = (u16*)(ws);                  // 20000*640 bf16 = 25.6e6 B
  u16* bufB = (u16*)(ws + 25600000);       // same
  u16* wrt = (u16*)(ws + 51200000);        // transposed bf16 weights
  u16* w1at = wrt + 256 * 256;
  u16* w1bt = w1at + 640 * 256;
  u16* w2at = w1bt + 640 * 640;
  u16* w2bt = w2at + 320 * 640;
  u16* w3at = w2bt + 320 * 320;
  u16* w3bt = w3at + 256 * 320;
  int* row_start = (int*)(ws + 53387264);  // NN+1 ints (padded to 20004)
  int* cursor = row_start + 20004;         // NN ints
  int* csr_src = cursor + NN;              // NE ints
  int* counts = csr_src + NE;              // NN ints

  const int* esrc = eidx;
  const int* edst = eidx + NE;

  // CSR build (reused by all 3 layers)
  hipMemsetAsync(counts, 0, NN * sizeof(int), stream);
  k_hist<<<(NE + 255) / 256, 256, 0, stream>>>(edst, counts, NE);
  k_scan<<<1, 1024, 0, stream>>>(counts, row_start, cursor);
  k_scatter<<<(NE + 255) / 256, 256, 0, stream>>>(esrc, edst, cursor, csr_src, NE);

  // fused prep: features->bf16 + all weight transposes (one dispatch)
  k_prep<<<9272, 256, 0, stream>>>(features, bufA, wr, w1a, w1b, w2a, w2b, w3a,
                                   w3b, wrt, w1at, w1bt, w2at, w2bt, w3at, w3bt);

  float* out_x = (float*)d_out;
  float* out_res = (float*)d_out + (size_t)NN * 256;

  // res = elu(X @ Wr + br)
  k_gemm<64, 256, 256, 1, true><<<dim3(313 * 2), 256, 0, stream>>>(bufA, wrt, br, out_res, NN);
  // L1: h0 = X + agg(X)  (aggregate in 256-dim, before the up-projection)
  k_agg<256, 0><<<2500, 256, 0, stream>>>(bufA, row_start, csr_src, nullptr, bufB);
  // t1 = elu(h0 @ w1a + b1a)
  k_gemm<64, 256, 640, 1, false><<<dim3(313 * 5), 256, 0, stream>>>(bufB, w1at, b1a, bufA, NN);
  // x1 = elu(elu(t1 @ w1b + b1b))
  k_gemm<64, 640, 640, 2, false><<<dim3(313 * 5), 256, 0, stream>>>(bufA, w1bt, b1b, bufB, NN);
  // L2 (agg commuted past w2a): y2 = x1 @ w2a   [320-dim, no bias/act]
  k_gemm<64, 640, 320, 0, false><<<dim3(313 * 3), 256, 0, stream>>>(bufB, w2at, nullptr, bufA, NN);
  // t2 = elu(y2 + agg(y2) + b2a)
  k_agg<320, 1><<<3125, 256, 0, stream>>>(bufA, row_start, csr_src, b2a, bufB);
  // x2 = elu(elu(t2 @ w2b + b2b))
  k_gemm<64, 320, 320, 2, false><<<dim3(313 * 3), 256, 0, stream>>>(bufB, w2bt, b2b, bufA, NN);
  // L3 (agg commuted past w3a): y3 = x2 @ w3a   [256-dim]
  k_gemm<64, 320, 256, 0, false><<<dim3(313 * 2), 256, 0, stream>>>(bufA, w3at, nullptr, bufB, NN);
  // t3 = elu(y3 + agg(y3) + b3a)
  k_agg<256, 1><<<2500, 256, 0, stream>>>(bufB, row_start, csr_src, b3a, bufA);
  // x = elu(t3 @ w3b + b3b)
  k_gemm<64, 256, 256, 1, true><<<dim3(313 * 2), 256, 0, stream>>>(bufA, w3bt, b3b, out_x, NN);
}

// Round 6
// 257.695 us; speedup vs baseline: 1.8993x; 1.0454x over previous
//
#include <hip/hip_runtime.h>
#include <cstdint>
#include <cstddef>

#define NN 20000
#define NE 320000

typedef short short8 __attribute__((ext_vector_type(8)));
typedef float f32x4 __attribute__((ext_vector_type(4)));
typedef unsigned short u16;

__device__ __forceinline__ float b2f(u16 u) {
  union { unsigned int i; float f; } z; z.i = ((unsigned int)u) << 16; return z.f;
}
__device__ __forceinline__ u16 f2b(float f) {
  union { float f; unsigned int i; } z; z.f = f;
  unsigned int r = z.i + 0x7fffu + ((z.i >> 16) & 1u);
  return (u16)(r >> 16);
}
// fast ELU: v_exp_f32-based, not libm expm1f
__device__ __forceinline__ float eluf(float v) {
  return v > 0.0f ? v : __expf(v) - 1.0f;
}

// ------- fused prep: features f2b (column-SLICED out) + 7 weight transposes
//         + edge histogram. virtual tid space:
//         [0,1280000): f2b 4 elems ; [1280000,1600000): hist ; rest: weights.
__global__ __launch_bounds__(256) void k_prep(
    const float* __restrict__ features, u16* __restrict__ xbf_sliced,
    const int* __restrict__ edst, int* __restrict__ counts,
    const float* __restrict__ wr, const float* __restrict__ w1a,
    const float* __restrict__ w1b, const float* __restrict__ w2a,
    const float* __restrict__ w2b, const float* __restrict__ w3a,
    const float* __restrict__ w3b,
    u16* __restrict__ wrt, u16* __restrict__ w1at, u16* __restrict__ w1bt,
    u16* __restrict__ w2at, u16* __restrict__ w2bt, u16* __restrict__ w3at,
    u16* __restrict__ w3bt) {
  int tid = blockIdx.x * 256 + threadIdx.x;
  if (tid < 1280000) {
    int node = tid >> 6;
    int c4 = (tid & 63) * 4;           // col = c4..c4+3 (within one 64-slice)
    float4 v = *reinterpret_cast<const float4*>(features + (size_t)node * 256 + c4);
    ushort4 o;
    o.x = f2b(v.x); o.y = f2b(v.y); o.z = f2b(v.z); o.w = f2b(v.w);
    int slice = c4 >> 6, within = c4 & 63;
    *reinterpret_cast<ushort4*>(xbf_sliced + (size_t)slice * NN * 64 +
                                (size_t)node * 64 + within) = o;
    return;
  }
  if (tid < 1600000) {
    atomicAdd(&counts[edst[tid - 1280000]], 1);
    return;
  }
  int r = tid - 1600000;
  const float* Ws[7] = {wr, w1a, w1b, w2a, w2b, w3a, w3b};
  u16* Wts[7] = {wrt, w1at, w1bt, w2at, w2bt, w3at, w3bt};
  const int Kd[7] = {256, 256, 640, 640, 320, 320, 256};
  const int Nd[7] = {256, 640, 640, 320, 320, 256, 256};
  const int cnt[7] = {65536, 163840, 409600, 204800, 102400, 81920, 65536};
#pragma unroll
  for (int j = 0; j < 7; ++j) {
    if (r < cnt[j]) {
      int n = r / Kd[j], k = r - n * Kd[j];
      Wts[j][r] = f2b(Ws[j][(size_t)k * Nd[j] + n]);
      return;
    }
    r -= cnt[j];
  }
}

// x4-vectorized single-block scan; writes exclusive prefix to BOTH rs and cur.
__global__ __launch_bounds__(1024) void k_scan(const int* __restrict__ counts,
                                               int* __restrict__ rs,
                                               int* __restrict__ cur) {
  __shared__ int wsum[16];
  __shared__ int carry_s;
  int t = threadIdx.x;
  int l = t & 63, w = t >> 6;
  if (t == 0) carry_s = 0;
  __syncthreads();
  for (int base = 0; base < NN; base += 4096) {
    int idx = base + t * 4;
    int4 v = {0, 0, 0, 0};
    if (idx < NN) v = *reinterpret_cast<const int4*>(counts + idx);
    int p0 = v.x, p1 = p0 + v.y, p2 = p1 + v.z, p3 = p2 + v.w;
    int incl = p3;
#pragma unroll
    for (int off = 1; off < 64; off <<= 1) {
      int u = __shfl_up(incl, off, 64);
      if (l >= off) incl += u;
    }
    if (l == 63) wsum[w] = incl;
    __syncthreads();  // (A) wsum ready
    int carry = carry_s;
    int wpre = 0;
    for (int k2 = 0; k2 < w; ++k2) wpre += wsum[k2];
    int tot = 0;
    if (t == 0)
      for (int k2 = 0; k2 < 16; ++k2) tot += wsum[k2];
    int ex = carry + wpre + incl - p3;
    if (idx < NN) {
      int4 o;
      o.x = ex; o.y = ex + p0; o.z = ex + p1; o.w = ex + p2;
      *reinterpret_cast<int4*>(rs + idx) = o;
      *reinterpret_cast<int4*>(cur + idx) = o;
    }
    __syncthreads();  // (B) all reads of wsum/carry_s done
    if (t == 0) carry_s = carry + tot;
    __syncthreads();  // (C) carry_s updated
  }
  if (t == 0) rs[NN] = carry_s;
}

__global__ __launch_bounds__(256) void k_scatter(const int* __restrict__ src,
                                                 const int* __restrict__ dst,
                                                 int* __restrict__ cursor,
                                                 int* __restrict__ csr_src, int ne) {
  int i = blockIdx.x * 256 + threadIdx.x;
  if (i >= ne) return;
  int d = dst[i];
  int p = atomicAdd(&cursor[d], 1);
  csr_src[p] = src[i];
}

// ---- aggregation, COLUMN-SLICED gather source ------------------------------
// xs layout: [4][NN][SW] bf16 (SW = D/4). Block's slice = (blockIdx&7)&3 so —
// under round-robin blockIdx->XCD dispatch — each XCD gathers from ONE slice
// (2.56-3.2MB) that stays resident in its 4MB L2 (kills the 8x L3 refetch).
// Classes {c, c+4} share slice c&3, splitting the node range in half.
// Output h is NORMAL [NN][D] layout. ACT=0: identity; ACT=1: elu(v+bias).
template <int D, int ACT>
__global__ __launch_bounds__(256) void k_agg(const u16* __restrict__ xs,
                                             const int* __restrict__ rs,
                                             const int* __restrict__ cs,
                                             const float* __restrict__ bias,
                                             u16* __restrict__ h) {
  constexpr int SW = D / 4;       // slice width (64 or 80 cols)
  constexpr int NCs = SW / 8;     // 16B chunks per slice-row (8 or 10)
  constexpr int NPB = 256 / NCs;  // nodes per block (32 or 25)
  int b = blockIdx.x;
  int cls = b & 7;
  int slice = cls & 3;
  int half = cls >> 2;
  int t = threadIdx.x;
  int nl = t / NCs, ch = t - nl * NCs;
  if (nl >= NPB) return;  // only when 256 % NCs != 0
  int node = half * 10000 + (b >> 3) * NPB + nl;
  if (node >= (half ? NN : 10000)) return;
  const u16* xp = xs + (size_t)slice * NN * SW + (size_t)ch * 8;
  float acc[8];
  {
    short8 v = *reinterpret_cast<const short8*>(xp + (size_t)node * SW);
#pragma unroll
    for (int q = 0; q < 8; ++q) acc[q] = b2f((u16)v[q]);
  }
  int e0 = rs[node], e1 = rs[node + 1];
  int e = e0;
  // 8-wide unroll: 8 independent index loads + 8 independent gathers in flight
  for (; e + 8 <= e1; e += 8) {
    int s[8];
#pragma unroll
    for (int u = 0; u < 8; ++u) s[u] = cs[e + u];
    short8 v[8];
#pragma unroll
    for (int u = 0; u < 8; ++u)
      v[u] = *reinterpret_cast<const short8*>(xp + (size_t)s[u] * SW);
#pragma unroll
    for (int q = 0; q < 8; ++q) {
      float a0 = b2f((u16)v[0][q]) + b2f((u16)v[1][q]);
      float a1 = b2f((u16)v[2][q]) + b2f((u16)v[3][q]);
      float a2 = b2f((u16)v[4][q]) + b2f((u16)v[5][q]);
      float a3 = b2f((u16)v[6][q]) + b2f((u16)v[7][q]);
      acc[q] += (a0 + a1) + (a2 + a3);
    }
  }
  for (; e + 4 <= e1; e += 4) {
    int s0 = cs[e], s1 = cs[e + 1], s2 = cs[e + 2], s3 = cs[e + 3];
    short8 v0 = *reinterpret_cast<const short8*>(xp + (size_t)s0 * SW);
    short8 v1 = *reinterpret_cast<const short8*>(xp + (size_t)s1 * SW);
    short8 v2 = *reinterpret_cast<const short8*>(xp + (size_t)s2 * SW);
    short8 v3 = *reinterpret_cast<const short8*>(xp + (size_t)s3 * SW);
#pragma unroll
    for (int q = 0; q < 8; ++q)
      acc[q] += (b2f((u16)v0[q]) + b2f((u16)v1[q])) + (b2f((u16)v2[q]) + b2f((u16)v3[q]));
  }
  for (; e < e1; ++e) {
    int s = cs[e];
    short8 v = *reinterpret_cast<const short8*>(xp + (size_t)s * SW);
#pragma unroll
    for (int q = 0; q < 8; ++q) acc[q] += b2f((u16)v[q]);
  }
  int col0 = slice * SW + ch * 8;
  if (ACT == 1) {
    float4 b0 = *reinterpret_cast<const float4*>(bias + col0);
    float4 b1 = *reinterpret_cast<const float4*>(bias + col0 + 4);
    acc[0] = eluf(acc[0] + b0.x); acc[1] = eluf(acc[1] + b0.y);
    acc[2] = eluf(acc[2] + b0.z); acc[3] = eluf(acc[3] + b0.w);
    acc[4] = eluf(acc[4] + b1.x); acc[5] = eluf(acc[5] + b1.y);
    acc[6] = eluf(acc[6] + b1.z); acc[7] = eluf(acc[7] + b1.w);
  }
  short8 o;
#pragma unroll
  for (int q = 0; q < 8; ++q) o[q] = (short)f2b(acc[q]);
  *reinterpret_cast<short8*>(h + (size_t)node * D + col0) = o;
}

// ---------------- GEMM: C = act(A[M][K] @ B[K][N] + bias) ----------------
// A bf16 [M][K] (or column-sliced [4][M][64] when INS), Bt bf16 [N][K].
// BMx128 tile, BK=32, 3-deep prefetch ring with counted vmcnt + raw s_barrier
// (T3/T4), setprio around MFMA (T5), 4 waves (2x2), 16x16x32 bf16 MFMA,
// swizzled LDS, XCD-chunked grid.
// ACT: 0 = none (no bias), 1 = elu(v+bias), 2 = elu(elu(v+bias)).
// OSW: 0 = normal [M][N] out; else column-sliced [4][M][OSW] bf16 out.
template <int BM, int K, int N, int ACT, bool OUTF32, bool INS, int OSW>
__global__ __launch_bounds__(256) void k_gemm(const u16* __restrict__ A,
                                              const u16* __restrict__ Bt,
                                              const float* __restrict__ bias,
                                              void* __restrict__ outp, int M) {
  constexpr int NBY = (N + 127) / 128;
  constexpr int NK = K / 32;
  constexpr int ABUF = BM * 32;       // u16 per A LDS buffer
  constexpr int BUFSZ = ABUF + 4096;  // A + B per ring slot
  constexpr int MI = BM / 32;         // acc i-extent per wave (2 or 4)
  constexpr int LPT = BM / 64 + 2;    // global_load_lds per thread per stage
  __shared__ __align__(16) u16 smem[3 * BUFSZ];
  int t = threadIdx.x;
  int l = t & 63, w = t >> 6;
  int lm = l & 15, lk = l >> 4;

  // bijective XCD-chunked swizzle (m204)
  int nb = gridDim.x;
  int q8 = nb >> 3, r8 = nb & 7;
  int orig = blockIdx.x;
  int xcd = orig & 7, idx = orig >> 3;
  int wg = (xcd < r8 ? xcd * (q8 + 1) : r8 * (q8 + 1) + (xcd - r8) * q8) + idx;
  int m0 = (wg / NBY) * BM;
  int n0 = (wg % NBY) * 128;
  int wm = (w >> 1) * (BM / 2), wn = (w & 1) * 64;

  f32x4 acc[MI][4];
#pragma unroll
  for (int i = 0; i < MI; ++i)
#pragma unroll
    for (int j = 0; j < 4; ++j)
#pragma unroll
      for (int qq = 0; qq < 4; ++qq) acc[i][j][qq] = 0.0f;

  // stage one K-slab into ring slot; k-chunk pre-swizzled in the GLOBAL
  // source (rule #21)
  auto stage = [&](int buf, int kt) {
    int k0 = kt * 32;
    u16* As = smem + buf * BUFSZ;
    u16* Bs = As + ABUF;
#pragma unroll
    for (int it = 0; it < BM / 64; ++it) {  // A: BM*32 u16 / (256 thr * 8)
      int c = it * 256 + t;
      int row = c >> 2;
      int kc = (c & 3) ^ ((c >> 3) & 3);
      int ra = m0 + row; ra = ra < M ? ra : M - 1;
      const u16* ga;
      if (INS)  // column-sliced A: [4][M][64]; 32-col K-chunk stays in-slice
        ga = A + (size_t)(k0 >> 6) * NN * 64 + (size_t)ra * 64 + (k0 & 63) + kc * 8;
      else
        ga = A + (size_t)ra * K + k0 + kc * 8;
      __builtin_amdgcn_global_load_lds(
          (const __attribute__((address_space(1))) void*)ga,
          (__attribute__((address_space(3))) void*)(As + c * 8), 16, 0, 0);
    }
#pragma unroll
    for (int it = 0; it < 2; ++it) {        // B: 128*32 u16
      int c = it * 256 + t;
      int row = c >> 2;
      int kc = (c & 3) ^ ((c >> 3) & 3);
      int rb = n0 + row; rb = rb < N ? rb : N - 1;
      const u16* gb = Bt + (size_t)rb * K + k0 + kc * 8;
      __builtin_amdgcn_global_load_lds(
          (const __attribute__((address_space(1))) void*)gb,
          (__attribute__((address_space(3))) void*)(Bs + c * 8), 16, 0, 0);
    }
  };

  // swizzled read slot: ((row>>1)&3) == ((lm>>1)&3) for row = 16*m + lm
  int kidx = (lk ^ ((lm >> 1) & 3)) * 8;

  // 3-deep ring: stages kt+1, kt+2 stay in flight across the consume barrier.
  stage(0, 0);
  stage(1, 1);
  stage(2, 2);
  int buf = 0;
  for (int kt = 0; kt < NK; ++kt) {
    int rem = NK - 1 - kt;
    if (rem >= 2)
      asm volatile("s_waitcnt vmcnt(%0)" ::"n"(2 * LPT) : "memory");
    else if (rem == 1)
      asm volatile("s_waitcnt vmcnt(%0)" ::"n"(LPT) : "memory");
    else
      asm volatile("s_waitcnt vmcnt(0)" ::: "memory");
    __builtin_amdgcn_s_barrier();          // ring slot kt now complete everywhere
    asm volatile("" ::: "memory");         // pin ds_reads below the barrier
    const u16* As = smem + buf * BUFSZ;
    const u16* Bs = As + ABUF;
    short8 af[MI], bf[4];
#pragma unroll
    for (int i = 0; i < MI; ++i)
      af[i] = *reinterpret_cast<const short8*>(As + (wm + i * 16 + lm) * 32 + kidx);
#pragma unroll
    for (int j = 0; j < 4; ++j)
      bf[j] = *reinterpret_cast<const short8*>(Bs + (wn + j * 16 + lm) * 32 + kidx);
    __builtin_amdgcn_s_setprio(1);
#pragma unroll
    for (int i = 0; i < MI; ++i)
#pragma unroll
      for (int j = 0; j < 4; ++j)
        acc[i][j] = __builtin_amdgcn_mfma_f32_16x16x32_bf16(af[i], bf[j], acc[i][j], 0, 0, 0);
    __builtin_amdgcn_s_setprio(0);
    // drain this wave's ds_reads, then barrier: all waves done READING slot
    asm volatile("s_waitcnt lgkmcnt(0)" ::: "memory");
    __builtin_amdgcn_s_barrier();
    asm volatile("" ::: "memory");         // pin next stage below the barrier
    if (kt + 3 < NK) stage(buf, kt + 3);   // overwrite the slot just consumed
    buf = (buf == 2) ? 0 : buf + 1;
  }

  // epilogue. C/D frag layout: row = i*16 + lk*4 + qq, col = j*16 + lm.
  if (!OUTF32) {
    u16* ep = smem + w * (BM / 2) * 64;
#pragma unroll
    for (int j = 0; j < 4; ++j) {
      int col = n0 + wn + j * 16 + lm;
      float bv = (ACT > 0) ? bias[col < N ? col : N - 1] : 0.0f;
#pragma unroll
      for (int i = 0; i < MI; ++i)
#pragma unroll
        for (int qq = 0; qq < 4; ++qq) {
          float v = acc[i][j][qq];
          if (ACT > 0) { v += bv; v = eluf(v); }
          if (ACT == 2) v = eluf(v);
          ep[(i * 16 + lk * 4 + qq) * 64 + j * 16 + lm] = f2b(v);
        }
    }
    __syncthreads();
    u16* op = (u16*)outp;
#pragma unroll
    for (int u = 0; u < BM / 16; ++u) {
      int rrow = m0 + wm + u * 8 + (l >> 3);
      int col = n0 + wn + (l & 7) * 8;   // 8-col chunk, never crosses OSW bnd
      if (rrow < M && col < N) {
        short8 val = *reinterpret_cast<const short8*>(ep + u * 512 + l * 8);
        if (OSW) {
          int slice = col / OSW, within = col - slice * OSW;
          *reinterpret_cast<short8*>(op + (size_t)slice * NN * OSW +
                                     (size_t)rrow * OSW + within) = val;
        } else {
          *reinterpret_cast<short8*>(op + (size_t)rrow * N + col) = val;
        }
      }
    }
  } else {
    float* op = (float*)outp;
#pragma unroll
    for (int j = 0; j < 4; ++j) {
      int col = n0 + wn + j * 16 + lm;
      if (col >= N) continue;
      float bv = (ACT > 0) ? bias[col] : 0.0f;
#pragma unroll
      for (int i = 0; i < MI; ++i) {
        int rb = m0 + wm + i * 16 + lk * 4;
#pragma unroll
        for (int qq = 0; qq < 4; ++qq) {
          int rr = rb + qq;
          if (rr >= M) continue;
          float v = acc[i][j][qq];
          if (ACT > 0) { v += bv; v = eluf(v); }
          if (ACT == 2) v = eluf(v);
          op[(size_t)rr * N + col] = v;
        }
      }
    }
  }
}

extern "C" void kernel_launch(void* const* d_in, const int* in_sizes, int n_in,
                              void* d_out, int out_size, void* d_ws, size_t ws_size,
                              hipStream_t stream) {
  const float* features = (const float*)d_in[0];
  const int* eidx = (const int*)d_in[1];
  const float* w1a = (const float*)d_in[2];
  const float* b1a = (const float*)d_in[3];
  const float* w1b = (const float*)d_in[4];
  const float* b1b = (const float*)d_in[5];
  const float* w2a = (const float*)d_in[6];
  const float* b2a = (const float*)d_in[7];
  const float* w2b = (const float*)d_in[8];
  const float* b2b = (const float*)d_in[9];
  const float* w3a = (const float*)d_in[10];
  const float* b3a = (const float*)d_in[11];
  const float* w3b = (const float*)d_in[12];
  const float* b3b = (const float*)d_in[13];
  const float* wr = (const float*)d_in[14];
  const float* br = (const float*)d_in[15];

  char* ws = (char*)d_ws;
  u16* bufA = (u16*)(ws);                  // <= 25.6e6 B activations
  u16* bufB = (u16*)(ws + 25600000);       // same
  u16* wrt = (u16*)(ws + 51200000);        // transposed bf16 weights
  u16* w1at = wrt + 256 * 256;
  u16* w1bt = w1at + 640 * 256;
  u16* w2at = w1bt + 640 * 640;
  u16* w2bt = w2at + 320 * 640;
  u16* w3at = w2bt + 320 * 320;
  u16* w3bt = w3at + 256 * 320;
  int* row_start = (int*)(ws + 53387264);  // NN+1 ints (padded to 20004)
  int* cursor = row_start + 20004;         // NN ints
  int* csr_src = cursor + NN;              // NE ints
  int* counts = csr_src + NE;              // NN ints

  const int* esrc = eidx;
  const int* edst = eidx + NE;

  // CSR build + prep: memset -> (prep: f2b-sliced + wt + hist) -> scan -> scatter
  hipMemsetAsync(counts, 0, NN * sizeof(int), stream);
  k_prep<<<10523, 256, 0, stream>>>(features, bufA, edst, counts, wr, w1a, w1b,
                                    w2a, w2b, w3a, w3b, wrt, w1at, w1bt, w2at,
                                    w2bt, w3at, w3bt);
  k_scan<<<1, 1024, 0, stream>>>(counts, row_start, cursor);
  k_scatter<<<(NE + 255) / 256, 256, 0, stream>>>(esrc, edst, cursor, csr_src, NE);

  float* out_x = (float*)d_out;
  float* out_res = (float*)d_out + (size_t)NN * 256;

  // res = elu(X @ Wr + br)   (A = x column-sliced)
  k_gemm<64, 256, 256, 1, true, true, 0><<<dim3(313 * 2), 256, 0, stream>>>(bufA, wrt, br, out_res, NN);
  // L1: h0 = X + agg(X)   (gather sliced x -> normal h0)
  k_agg<256, 0><<<8 * 313, 256, 0, stream>>>(bufA, row_start, csr_src, nullptr, bufB);
  // t1 = elu(h0 @ w1a + b1a)
  k_gemm<64, 256, 640, 1, false, false, 0><<<dim3(313 * 5), 256, 0, stream>>>(bufB, w1at, b1a, bufA, NN);
  // x1 = elu(elu(t1 @ w1b + b1b))
  k_gemm<64, 640, 640, 2, false, false, 0><<<dim3(313 * 5), 256, 0, stream>>>(bufA, w1bt, b1b, bufB, NN);
  // L2 (agg commuted past w2a): y2 = x1 @ w2a   [320-dim, sliced out]
  k_gemm<64, 640, 320, 0, false, false, 80><<<dim3(313 * 3), 256, 0, stream>>>(bufB, w2at, nullptr, bufA, NN);
  // t2 = elu(y2 + agg(y2) + b2a)   (gather sliced y2 -> normal t2)
  k_agg<320, 1><<<8 * 400, 256, 0, stream>>>(bufA, row_start, csr_src, b2a, bufB);
  // x2 = elu(elu(t2 @ w2b + b2b))
  k_gemm<64, 320, 320, 2, false, false, 0><<<dim3(313 * 3), 256, 0, stream>>>(bufB, w2bt, b2b, bufA, NN);
  // L3 (agg commuted past w3a): y3 = x2 @ w3a   [256-dim, sliced out]
  k_gemm<64, 320, 256, 0, false, false, 64><<<dim3(313 * 2), 256, 0, stream>>>(bufA, w3at, nullptr, bufB, NN);
  // t3 = elu(y3 + agg(y3) + b3a)   (gather sliced y3 -> normal t3)
  k_agg<256, 1><<<8 * 313, 256, 0, stream>>>(bufB, row_start, csr_src, b3a, bufA);
  // x = elu(t3 @ w3b + b3b)
  k_gemm<64, 256, 256, 1, true, false, 0><<<dim3(313 * 2), 256, 0, stream>>>(bufA, w3bt, b3b, out_x, NN);
}